// Round 1
// baseline (479.176 us; speedup 1.0000x reference)
//
#include <hip/hip_runtime.h>

#define NEG_SLOPE 0.2f
#define EPS_F 1e-16f

// ---------------- Layer 1 GEMM: h1 = x @ W1   (N x 256) @ (256 x 64) ----------------
__global__ __launch_bounds__(256) void gemm1_kernel(const float* __restrict__ x,
                                                    const float* __restrict__ W1,
                                                    float* __restrict__ h1, int N) {
    __shared__ float xst[64][68];   // transposed x tile: xst[k][row], pad 68 (272B row, 16B aligned)
    __shared__ float wst[64][64];   // W chunk: wst[k][col]
    const int t = threadIdx.x;
    const int n0 = blockIdx.x * 64;
    const int ty = t >> 4, tx = t & 15;

    float4 acc[4];
    acc[0] = make_float4(0.f, 0.f, 0.f, 0.f);
    acc[1] = acc[0]; acc[2] = acc[0]; acc[3] = acc[0];

    for (int kc = 0; kc < 256; kc += 64) {
        // load x tile (64 rows x 64 k) transposed into LDS
        #pragma unroll
        for (int ii = 0; ii < 4; ++ii) {
            int fidx = (ii * 256 + t) * 4;
            int row = fidx >> 6;
            int kk = fidx & 63;
            int grow = n0 + row;
            float4 v = make_float4(0.f, 0.f, 0.f, 0.f);
            if (grow < N) v = *reinterpret_cast<const float4*>(&x[grow * 256 + kc + kk]);
            xst[kk + 0][row] = v.x;
            xst[kk + 1][row] = v.y;
            xst[kk + 2][row] = v.z;
            xst[kk + 3][row] = v.w;
        }
        // load W1 chunk (64 k x 64 cols)
        #pragma unroll
        for (int ii = 0; ii < 4; ++ii) {
            int fidx = (ii * 256 + t) * 4;
            int k = fidx >> 6;
            int c = fidx & 63;
            *reinterpret_cast<float4*>(&wst[k][c]) =
                *reinterpret_cast<const float4*>(&W1[(kc + k) * 64 + c]);
        }
        __syncthreads();
        #pragma unroll
        for (int k = 0; k < 64; ++k) {
            float4 xv = *reinterpret_cast<const float4*>(&xst[k][ty * 4]);
            float4 wv = *reinterpret_cast<const float4*>(&wst[k][tx * 4]);
            acc[0].x = fmaf(xv.x, wv.x, acc[0].x);
            acc[0].y = fmaf(xv.x, wv.y, acc[0].y);
            acc[0].z = fmaf(xv.x, wv.z, acc[0].z);
            acc[0].w = fmaf(xv.x, wv.w, acc[0].w);
            acc[1].x = fmaf(xv.y, wv.x, acc[1].x);
            acc[1].y = fmaf(xv.y, wv.y, acc[1].y);
            acc[1].z = fmaf(xv.y, wv.z, acc[1].z);
            acc[1].w = fmaf(xv.y, wv.w, acc[1].w);
            acc[2].x = fmaf(xv.z, wv.x, acc[2].x);
            acc[2].y = fmaf(xv.z, wv.y, acc[2].y);
            acc[2].z = fmaf(xv.z, wv.z, acc[2].z);
            acc[2].w = fmaf(xv.z, wv.w, acc[2].w);
            acc[3].x = fmaf(xv.w, wv.x, acc[3].x);
            acc[3].y = fmaf(xv.w, wv.y, acc[3].y);
            acc[3].z = fmaf(xv.w, wv.z, acc[3].z);
            acc[3].w = fmaf(xv.w, wv.w, acc[3].w);
        }
        __syncthreads();
    }
    #pragma unroll
    for (int i = 0; i < 4; ++i) {
        int row = n0 + ty * 4 + i;
        if (row < N) {
            *reinterpret_cast<float4*>(&h1[row * 64 + tx * 4]) = acc[i];
        }
    }
}

// ---------------- alpha1: per-node per-head attention dots ----------------
__global__ __launch_bounds__(256) void alpha1_kernel(const float* __restrict__ h1,
                                                     const float* __restrict__ a_src,
                                                     const float* __restrict__ a_dst,
                                                     float* __restrict__ as1,
                                                     float* __restrict__ ad1, int N) {
    int tid = blockIdx.x * 256 + threadIdx.x;
    int node = tid >> 3;
    int h = tid & 7;
    if (node >= N) return;
    float4 v0 = *reinterpret_cast<const float4*>(&h1[node * 64 + h * 8]);
    float4 v1 = *reinterpret_cast<const float4*>(&h1[node * 64 + h * 8 + 4]);
    float4 s0 = *reinterpret_cast<const float4*>(&a_src[h * 8]);
    float4 s1 = *reinterpret_cast<const float4*>(&a_src[h * 8 + 4]);
    float4 d0 = *reinterpret_cast<const float4*>(&a_dst[h * 8]);
    float4 d1 = *reinterpret_cast<const float4*>(&a_dst[h * 8 + 4]);
    float s = v0.x * s0.x + v0.y * s0.y + v0.z * s0.z + v0.w * s0.w
            + v1.x * s1.x + v1.y * s1.y + v1.z * s1.z + v1.w * s1.w;
    float d = v0.x * d0.x + v0.y * d0.y + v0.z * d0.z + v0.w * d0.w
            + v1.x * d1.x + v1.y * d1.y + v1.z * d1.z + v1.w * d1.w;
    as1[tid] = s;
    ad1[tid] = d;
}

// ---------------- degree histogram ----------------
__global__ __launch_bounds__(256) void degree_kernel(const int* __restrict__ dst,
                                                     int* __restrict__ deg, int E) {
    int i = blockIdx.x * 256 + threadIdx.x;
    if (i < E) atomicAdd(&deg[dst[i]], 1);
}

// ---------------- exclusive scan (3 phases), chunk = 1024/block ----------------
__global__ __launch_bounds__(256) void scan1_kernel(const int* __restrict__ deg,
                                                    int* __restrict__ row_ptr,
                                                    int* __restrict__ bsum, int N) {
    __shared__ int sdata[256];
    int t = threadIdx.x;
    int base = blockIdx.x * 1024 + t * 4;
    int d0 = (base + 0 < N) ? deg[base + 0] : 0;
    int d1 = (base + 1 < N) ? deg[base + 1] : 0;
    int d2 = (base + 2 < N) ? deg[base + 2] : 0;
    int d3 = (base + 3 < N) ? deg[base + 3] : 0;
    int s = d0 + d1 + d2 + d3;
    int val = s;
    sdata[t] = val;
    __syncthreads();
    for (int off = 1; off < 256; off <<= 1) {
        int add = (t >= off) ? sdata[t - off] : 0;
        __syncthreads();
        val += add;
        sdata[t] = val;
        __syncthreads();
    }
    int excl = val - s;
    if (base + 0 < N) row_ptr[base + 0] = excl;
    if (base + 1 < N) row_ptr[base + 1] = excl + d0;
    if (base + 2 < N) row_ptr[base + 2] = excl + d0 + d1;
    if (base + 3 < N) row_ptr[base + 3] = excl + d0 + d1 + d2;
    if (t == 255) bsum[blockIdx.x] = val;
}

__global__ void scan2_kernel(int* __restrict__ bsum, int nb) {
    if (threadIdx.x == 0 && blockIdx.x == 0) {
        int run = 0;
        for (int i = 0; i < nb; ++i) { int v = bsum[i]; bsum[i] = run; run += v; }
    }
}

__global__ __launch_bounds__(256) void scan3_kernel(int* __restrict__ row_ptr,
                                                    const int* __restrict__ bsum,
                                                    int N, int E) {
    int base = blockIdx.x * 1024 + threadIdx.x * 4;
    int off = bsum[blockIdx.x];
    if (base + 0 < N) row_ptr[base + 0] += off;
    if (base + 1 < N) row_ptr[base + 1] += off;
    if (base + 2 < N) row_ptr[base + 2] += off;
    if (base + 3 < N) row_ptr[base + 3] += off;
    if (blockIdx.x == 0 && threadIdx.x == 0) row_ptr[N] = E;
}

// ---------------- CSR fill (sort edges by dst) ----------------
__global__ __launch_bounds__(256) void fill_kernel(const int* __restrict__ src,
                                                   const int* __restrict__ dst,
                                                   const int* __restrict__ row_ptr,
                                                   int* __restrict__ cursor,
                                                   int* __restrict__ csr_src, int E) {
    int i = blockIdx.x * 256 + threadIdx.x;
    if (i < E) {
        int d = dst[i];
        int pos = row_ptr[d] + atomicAdd(&cursor[d], 1);
        csr_src[pos] = src[i];
    }
}

// ---------------- layer-1 gather: softmax-aggregate + bias + ELU ----------------
// one wave per dst node; lane = head*8 + dim
__global__ __launch_bounds__(256) void gat1_kernel(const float* __restrict__ h1,
                                                   const float* __restrict__ as1,
                                                   const float* __restrict__ ad1,
                                                   const int* __restrict__ row_ptr,
                                                   const int* __restrict__ csr_src,
                                                   const float* __restrict__ b1,
                                                   float* __restrict__ h2, int N) {
    int dst = blockIdx.x * 4 + (threadIdx.x >> 6);
    if (dst >= N) return;
    int lane = threadIdx.x & 63;
    int h = lane >> 3;
    float ad = ad1[dst * 8 + h];
    int start = row_ptr[dst];
    int end = row_ptr[dst + 1];
    float acc = 0.f, ssum = 0.f;
    for (int i = start; i < end; ++i) {
        int src = csr_src[i];
        float as = as1[src * 8 + h];
        float e = as + ad;
        e = (e > 0.f) ? e : NEG_SLOPE * e;
        float ex = __expf(e);
        float hv = h1[src * 64 + lane];
        acc = fmaf(ex, hv, acc);
        ssum += ex;
    }
    float out = acc / (ssum + EPS_F) + b1[lane];
    float h2v = (out > 0.f) ? out : (__expf(out) - 1.f);  // ELU
    h2[dst * 64 + lane] = h2v;
}

// ---------------- Layer 2 GEMM: g2 = h2 @ W2  (N x 64)@(64 x 16), + alpha2 dots ----------------
__global__ __launch_bounds__(256) void gemm2_kernel(const float* __restrict__ h2,
                                                    const float* __restrict__ W2,
                                                    const float* __restrict__ a2_src,
                                                    const float* __restrict__ a2_dst,
                                                    float* __restrict__ g2,
                                                    float* __restrict__ as2,
                                                    float* __restrict__ ad2, int N) {
    __shared__ float hs[64][68];
    __shared__ float ws[1024];
    int t = threadIdx.x;
    int n0 = blockIdx.x * 64;
    // W2: 64x16 = 1024 floats, one float4 per thread
    *reinterpret_cast<float4*>(&ws[t * 4]) = *reinterpret_cast<const float4*>(&W2[t * 4]);
    #pragma unroll
    for (int ii = 0; ii < 4; ++ii) {
        int fidx = (ii * 256 + t) * 4;
        int row = fidx >> 6;
        int col = fidx & 63;
        float4 v = make_float4(0.f, 0.f, 0.f, 0.f);
        if (n0 + row < N) v = *reinterpret_cast<const float4*>(&h2[(n0 + row) * 64 + col]);
        *reinterpret_cast<float4*>(&hs[row][col]) = v;
    }
    __syncthreads();
    int node = t >> 2, j4 = t & 3;
    float4 acc = make_float4(0.f, 0.f, 0.f, 0.f);
    #pragma unroll
    for (int k = 0; k < 64; ++k) {
        float hk = hs[node][k];
        float4 w = *reinterpret_cast<const float4*>(&ws[k * 16 + j4 * 4]);
        acc.x = fmaf(hk, w.x, acc.x);
        acc.y = fmaf(hk, w.y, acc.y);
        acc.z = fmaf(hk, w.z, acc.z);
        acc.w = fmaf(hk, w.w, acc.w);
    }
    float4 asv = *reinterpret_cast<const float4*>(&a2_src[j4 * 4]);
    float4 adv = *reinterpret_cast<const float4*>(&a2_dst[j4 * 4]);
    float ps = acc.x * asv.x + acc.y * asv.y + acc.z * asv.z + acc.w * asv.w;
    float pd = acc.x * adv.x + acc.y * adv.y + acc.z * adv.z + acc.w * adv.w;
    ps += __shfl_xor(ps, 1); ps += __shfl_xor(ps, 2);
    pd += __shfl_xor(pd, 1); pd += __shfl_xor(pd, 2);
    int gnode = n0 + node;
    if (gnode < N) {
        *reinterpret_cast<float4*>(&g2[gnode * 16 + j4 * 4]) = acc;
        if (j4 == 0) { as2[gnode] = ps; ad2[gnode] = pd; }
    }
}

// ---------------- layer-2 gather + bias + log_softmax ----------------
// one wave per dst; 64 lanes = 4 edge-slots x 16 dims
__global__ __launch_bounds__(256) void gat2_kernel(const float* __restrict__ g2,
                                                   const float* __restrict__ as2,
                                                   const float* __restrict__ ad2,
                                                   const int* __restrict__ row_ptr,
                                                   const int* __restrict__ csr_src,
                                                   const float* __restrict__ b2,
                                                   float* __restrict__ out, int N) {
    int dst = blockIdx.x * 4 + (threadIdx.x >> 6);
    if (dst >= N) return;
    int lane = threadIdx.x & 63;
    int slot = lane >> 4, j = lane & 15;
    float ad = ad2[dst];
    int start = row_ptr[dst];
    int end = row_ptr[dst + 1];
    float acc = 0.f, ssum = 0.f;
    for (int i = start + slot; i < end; i += 4) {
        int src = csr_src[i];
        float as = as2[src];
        float e = as + ad;
        e = (e > 0.f) ? e : NEG_SLOPE * e;
        float ex = __expf(e);
        acc = fmaf(ex, g2[src * 16 + j], acc);
        ssum += ex;
    }
    acc += __shfl_xor(acc, 16); acc += __shfl_xor(acc, 32);
    ssum += __shfl_xor(ssum, 16); ssum += __shfl_xor(ssum, 32);
    float v = acc / (ssum + EPS_F) + b2[j];
    // log_softmax over the 16 dims (all lanes hold full row now)
    float m = v;
    for (int off = 1; off < 16; off <<= 1) m = fmaxf(m, __shfl_xor(m, off));
    float ev = __expf(v - m);
    float se = ev;
    for (int off = 1; off < 16; off <<= 1) se += __shfl_xor(se, off);
    float ls = v - m - logf(se);
    if (lane < 16) {
        out[(size_t)dst * 16 + j] = v;
        out[(size_t)N * 16 + (size_t)dst * 16 + j] = ls;
    }
}

extern "C" void kernel_launch(void* const* d_in, const int* in_sizes, int n_in,
                              void* d_out, int out_size, void* d_ws, size_t ws_size,
                              hipStream_t stream) {
    const float* x      = (const float*)d_in[0];
    const int*   eidx   = (const int*)d_in[1];
    const float* W1     = (const float*)d_in[2];
    const float* a1_src = (const float*)d_in[3];
    const float* a1_dst = (const float*)d_in[4];
    const float* b1     = (const float*)d_in[5];
    const float* W2     = (const float*)d_in[6];
    const float* a2_src = (const float*)d_in[7];
    const float* a2_dst = (const float*)d_in[8];
    const float* b2     = (const float*)d_in[9];

    const int N = in_sizes[0] / 256;
    const int E = in_sizes[1] / 2;
    const int* esrc = eidx;
    const int* edst = eidx + E;

    char* ws = (char*)d_ws;
    size_t off = 0;
    auto alloc = [&](size_t bytes) -> void* {
        void* p = ws + off;
        off += (bytes + 255) & ~size_t(255);
        return p;
    };
    float* h1     = (float*)alloc((size_t)N * 64 * 4);
    float* as1    = (float*)alloc((size_t)N * 8 * 4);
    float* ad1    = (float*)alloc((size_t)N * 8 * 4);
    float* h2     = (float*)alloc((size_t)N * 64 * 4);
    float* g2     = (float*)alloc((size_t)N * 16 * 4);
    float* as2    = (float*)alloc((size_t)N * 4);
    float* ad2    = (float*)alloc((size_t)N * 4);
    int* deg      = (int*)alloc((size_t)N * 4);
    int* row_ptr  = (int*)alloc((size_t)(N + 1) * 4);
    int* cursor   = (int*)alloc((size_t)N * 4);
    int* csr_src  = (int*)alloc((size_t)E * 4);
    const int nb  = (N + 1023) / 1024;
    int* bsum     = (int*)alloc((size_t)nb * 4);

    hipMemsetAsync(deg, 0, (size_t)N * 4, stream);
    hipMemsetAsync(cursor, 0, (size_t)N * 4, stream);

    gemm1_kernel<<<(N + 63) / 64, 256, 0, stream>>>(x, W1, h1, N);
    alpha1_kernel<<<(N * 8 + 255) / 256, 256, 0, stream>>>(h1, a1_src, a1_dst, as1, ad1, N);
    degree_kernel<<<(E + 255) / 256, 256, 0, stream>>>(edst, deg, E);
    scan1_kernel<<<nb, 256, 0, stream>>>(deg, row_ptr, bsum, N);
    scan2_kernel<<<1, 64, 0, stream>>>(bsum, nb);
    scan3_kernel<<<nb, 256, 0, stream>>>(row_ptr, bsum, N, E);
    fill_kernel<<<(E + 255) / 256, 256, 0, stream>>>(esrc, edst, row_ptr, cursor, csr_src, E);
    gat1_kernel<<<(N + 3) / 4, 256, 0, stream>>>(h1, as1, ad1, row_ptr, csr_src, b1, h2, N);
    gemm2_kernel<<<(N + 63) / 64, 256, 0, stream>>>(h2, W2, a2_src, a2_dst, g2, as2, ad2, N);
    gat2_kernel<<<(N + 3) / 4, 256, 0, stream>>>(g2, as2, ad2, row_ptr, csr_src, b2, (float*)d_out, N);
}

// Round 2
// 409.869 us; speedup vs baseline: 1.1691x; 1.1691x over previous
//
#include <hip/hip_runtime.h>

#define NEG_SLOPE 0.2f
#define EPS_F 1e-16f

// ---------------- Layer 1 GEMM: h1 = x @ W1   (N x 256) @ (256 x 64) ----------------
__global__ __launch_bounds__(256) void gemm1_kernel(const float* __restrict__ x,
                                                    const float* __restrict__ W1,
                                                    float* __restrict__ h1, int N) {
    __shared__ float xst[64][68];   // transposed x tile
    __shared__ float wst[64][64];   // W chunk
    const int t = threadIdx.x;
    const int n0 = blockIdx.x * 64;
    const int ty = t >> 4, tx = t & 15;

    float4 acc[4];
    acc[0] = make_float4(0.f, 0.f, 0.f, 0.f);
    acc[1] = acc[0]; acc[2] = acc[0]; acc[3] = acc[0];

    for (int kc = 0; kc < 256; kc += 64) {
        #pragma unroll
        for (int ii = 0; ii < 4; ++ii) {
            int fidx = (ii * 256 + t) * 4;
            int row = fidx >> 6;
            int kk = fidx & 63;
            int grow = n0 + row;
            float4 v = make_float4(0.f, 0.f, 0.f, 0.f);
            if (grow < N) v = *reinterpret_cast<const float4*>(&x[grow * 256 + kc + kk]);
            xst[kk + 0][row] = v.x;
            xst[kk + 1][row] = v.y;
            xst[kk + 2][row] = v.z;
            xst[kk + 3][row] = v.w;
        }
        #pragma unroll
        for (int ii = 0; ii < 4; ++ii) {
            int fidx = (ii * 256 + t) * 4;
            int k = fidx >> 6;
            int c = fidx & 63;
            *reinterpret_cast<float4*>(&wst[k][c]) =
                *reinterpret_cast<const float4*>(&W1[(kc + k) * 64 + c]);
        }
        __syncthreads();
        #pragma unroll
        for (int k = 0; k < 64; ++k) {
            float4 xv = *reinterpret_cast<const float4*>(&xst[k][ty * 4]);
            float4 wv = *reinterpret_cast<const float4*>(&wst[k][tx * 4]);
            acc[0].x = fmaf(xv.x, wv.x, acc[0].x);
            acc[0].y = fmaf(xv.x, wv.y, acc[0].y);
            acc[0].z = fmaf(xv.x, wv.z, acc[0].z);
            acc[0].w = fmaf(xv.x, wv.w, acc[0].w);
            acc[1].x = fmaf(xv.y, wv.x, acc[1].x);
            acc[1].y = fmaf(xv.y, wv.y, acc[1].y);
            acc[1].z = fmaf(xv.y, wv.z, acc[1].z);
            acc[1].w = fmaf(xv.y, wv.w, acc[1].w);
            acc[2].x = fmaf(xv.z, wv.x, acc[2].x);
            acc[2].y = fmaf(xv.z, wv.y, acc[2].y);
            acc[2].z = fmaf(xv.z, wv.z, acc[2].z);
            acc[2].w = fmaf(xv.z, wv.w, acc[2].w);
            acc[3].x = fmaf(xv.w, wv.x, acc[3].x);
            acc[3].y = fmaf(xv.w, wv.y, acc[3].y);
            acc[3].z = fmaf(xv.w, wv.z, acc[3].z);
            acc[3].w = fmaf(xv.w, wv.w, acc[3].w);
        }
        __syncthreads();
    }
    #pragma unroll
    for (int i = 0; i < 4; ++i) {
        int row = n0 + ty * 4 + i;
        if (row < N) {
            *reinterpret_cast<float4*>(&h1[row * 64 + tx * 4]) = acc[i];
        }
    }
}

// ---------------- alpha1: per-node per-head dst attention dot only ----------------
__global__ __launch_bounds__(256) void alpha1_kernel(const float* __restrict__ h1,
                                                     const float* __restrict__ a_dst,
                                                     float* __restrict__ ad1, int N) {
    int tid = blockIdx.x * 256 + threadIdx.x;
    int node = tid >> 3;
    int h = tid & 7;
    if (node >= N) return;
    float4 v0 = *reinterpret_cast<const float4*>(&h1[node * 64 + h * 8]);
    float4 v1 = *reinterpret_cast<const float4*>(&h1[node * 64 + h * 8 + 4]);
    float4 d0 = *reinterpret_cast<const float4*>(&a_dst[h * 8]);
    float4 d1 = *reinterpret_cast<const float4*>(&a_dst[h * 8 + 4]);
    float d = v0.x * d0.x + v0.y * d0.y + v0.z * d0.z + v0.w * d0.w
            + v1.x * d1.x + v1.y * d1.y + v1.z * d1.z + v1.w * d1.w;
    ad1[tid] = d;
}

// ---------------- degree histogram ----------------
__global__ __launch_bounds__(256) void degree_kernel(const int* __restrict__ dst,
                                                     int* __restrict__ deg, int E) {
    int i = blockIdx.x * 256 + threadIdx.x;
    if (i < E) atomicAdd(&deg[dst[i]], 1);
}

// ---------------- exclusive scan (3 phases) ----------------
__global__ __launch_bounds__(256) void scan1_kernel(const int* __restrict__ deg,
                                                    int* __restrict__ row_ptr,
                                                    int* __restrict__ bsum, int N) {
    __shared__ int sdata[256];
    int t = threadIdx.x;
    int base = blockIdx.x * 1024 + t * 4;
    int d0 = (base + 0 < N) ? deg[base + 0] : 0;
    int d1 = (base + 1 < N) ? deg[base + 1] : 0;
    int d2 = (base + 2 < N) ? deg[base + 2] : 0;
    int d3 = (base + 3 < N) ? deg[base + 3] : 0;
    int s = d0 + d1 + d2 + d3;
    int val = s;
    sdata[t] = val;
    __syncthreads();
    for (int off = 1; off < 256; off <<= 1) {
        int add = (t >= off) ? sdata[t - off] : 0;
        __syncthreads();
        val += add;
        sdata[t] = val;
        __syncthreads();
    }
    int excl = val - s;
    if (base + 0 < N) row_ptr[base + 0] = excl;
    if (base + 1 < N) row_ptr[base + 1] = excl + d0;
    if (base + 2 < N) row_ptr[base + 2] = excl + d0 + d1;
    if (base + 3 < N) row_ptr[base + 3] = excl + d0 + d1 + d2;
    if (t == 255) bsum[blockIdx.x] = val;
}

__global__ void scan2_kernel(int* __restrict__ bsum, int nb) {
    if (threadIdx.x == 0 && blockIdx.x == 0) {
        int run = 0;
        for (int i = 0; i < nb; ++i) { int v = bsum[i]; bsum[i] = run; run += v; }
    }
}

__global__ __launch_bounds__(256) void scan3_kernel(int* __restrict__ row_ptr,
                                                    int* __restrict__ cursor,
                                                    const int* __restrict__ bsum,
                                                    int N, int E) {
    int base = blockIdx.x * 1024 + threadIdx.x * 4;
    int off = bsum[blockIdx.x];
    #pragma unroll
    for (int q = 0; q < 4; ++q) {
        if (base + q < N) {
            int v = row_ptr[base + q] + off;
            row_ptr[base + q] = v;
            cursor[base + q] = v;
        }
    }
    if (blockIdx.x == 0 && threadIdx.x == 0) row_ptr[N] = E;
}

// ---------------- CSR fill (single atomic per edge) ----------------
__global__ __launch_bounds__(256) void fill_kernel(const int* __restrict__ src,
                                                   const int* __restrict__ dst,
                                                   int* __restrict__ cursor,
                                                   int* __restrict__ csr_src, int E) {
    int i = blockIdx.x * 256 + threadIdx.x;
    if (i < E) {
        int pos = atomicAdd(&cursor[dst[i]], 1);
        csr_src[pos] = src[i];
    }
}

// ---------------- layer-1 gather: batched srcs + 4x unroll + in-wave src-dot ----------------
// one wave per dst node; lane = head*8 + dim
__global__ __launch_bounds__(256) void gat1_kernel(const float* __restrict__ h1,
                                                   const float* __restrict__ a1_src,
                                                   const float* __restrict__ ad1,
                                                   const int* __restrict__ row_ptr,
                                                   const int* __restrict__ csr_src,
                                                   const float* __restrict__ b1,
                                                   float* __restrict__ h2, int N) {
    int dst = blockIdx.x * 4 + (threadIdx.x >> 6);
    if (dst >= N) return;
    int lane = threadIdx.x & 63;
    int h = lane >> 3;
    float asv = a1_src[lane];            // a_src[h][d] for this lane
    float ad = ad1[dst * 8 + h];
    int start = row_ptr[dst];
    int end = row_ptr[dst + 1];
    float acc = 0.f, ssum = 0.f;
    int i = start;
    while (i < end) {
        int nb = end - i; if (nb > 64) nb = 64;
        int sreg = (lane < nb) ? csr_src[i + lane] : 0;   // 64 edge srcs, one coalesced load
        int k = 0;
        for (; k + 4 <= nb; k += 4) {
            int s0 = __shfl(sreg, k);
            int s1 = __shfl(sreg, k + 1);
            int s2 = __shfl(sreg, k + 2);
            int s3 = __shfl(sreg, k + 3);
            float v0 = h1[(size_t)s0 * 64 + lane];
            float v1 = h1[(size_t)s1 * 64 + lane];
            float v2 = h1[(size_t)s2 * 64 + lane];
            float v3 = h1[(size_t)s3 * 64 + lane];
            // src attention dot in-register: reduce over the 8 dims of this head
            float p0 = v0 * asv, p1 = v1 * asv, p2 = v2 * asv, p3 = v3 * asv;
            p0 += __shfl_xor(p0, 1); p0 += __shfl_xor(p0, 2); p0 += __shfl_xor(p0, 4);
            p1 += __shfl_xor(p1, 1); p1 += __shfl_xor(p1, 2); p1 += __shfl_xor(p1, 4);
            p2 += __shfl_xor(p2, 1); p2 += __shfl_xor(p2, 2); p2 += __shfl_xor(p2, 4);
            p3 += __shfl_xor(p3, 1); p3 += __shfl_xor(p3, 2); p3 += __shfl_xor(p3, 4);
            float e0 = p0 + ad; e0 = (e0 > 0.f) ? e0 : NEG_SLOPE * e0;
            float e1 = p1 + ad; e1 = (e1 > 0.f) ? e1 : NEG_SLOPE * e1;
            float e2 = p2 + ad; e2 = (e2 > 0.f) ? e2 : NEG_SLOPE * e2;
            float e3 = p3 + ad; e3 = (e3 > 0.f) ? e3 : NEG_SLOPE * e3;
            float x0 = __expf(e0), x1 = __expf(e1), x2 = __expf(e2), x3 = __expf(e3);
            acc = fmaf(x0, v0, acc); ssum += x0;
            acc = fmaf(x1, v1, acc); ssum += x1;
            acc = fmaf(x2, v2, acc); ssum += x2;
            acc = fmaf(x3, v3, acc); ssum += x3;
        }
        for (; k < nb; ++k) {
            int s0 = __shfl(sreg, k);
            float v0 = h1[(size_t)s0 * 64 + lane];
            float p0 = v0 * asv;
            p0 += __shfl_xor(p0, 1); p0 += __shfl_xor(p0, 2); p0 += __shfl_xor(p0, 4);
            float e0 = p0 + ad; e0 = (e0 > 0.f) ? e0 : NEG_SLOPE * e0;
            float x0 = __expf(e0);
            acc = fmaf(x0, v0, acc); ssum += x0;
        }
        i += nb;
    }
    float out = acc / (ssum + EPS_F) + b1[lane];
    float h2v = (out > 0.f) ? out : (__expf(out) - 1.f);  // ELU
    h2[(size_t)dst * 64 + lane] = h2v;
}

// ---------------- Layer 2 GEMM: g2 = h2 @ W2  (N x 64)@(64 x 16), + dst dot ----------------
__global__ __launch_bounds__(256) void gemm2_kernel(const float* __restrict__ h2,
                                                    const float* __restrict__ W2,
                                                    const float* __restrict__ a2_dst,
                                                    float* __restrict__ g2,
                                                    float* __restrict__ ad2, int N) {
    __shared__ float hs[64][68];
    __shared__ float ws[1024];
    int t = threadIdx.x;
    int n0 = blockIdx.x * 64;
    *reinterpret_cast<float4*>(&ws[t * 4]) = *reinterpret_cast<const float4*>(&W2[t * 4]);
    #pragma unroll
    for (int ii = 0; ii < 4; ++ii) {
        int fidx = (ii * 256 + t) * 4;
        int row = fidx >> 6;
        int col = fidx & 63;
        float4 v = make_float4(0.f, 0.f, 0.f, 0.f);
        if (n0 + row < N) v = *reinterpret_cast<const float4*>(&h2[(size_t)(n0 + row) * 64 + col]);
        *reinterpret_cast<float4*>(&hs[row][col]) = v;
    }
    __syncthreads();
    int node = t >> 2, j4 = t & 3;
    float4 acc = make_float4(0.f, 0.f, 0.f, 0.f);
    #pragma unroll
    for (int k = 0; k < 64; ++k) {
        float hk = hs[node][k];
        float4 w = *reinterpret_cast<const float4*>(&ws[k * 16 + j4 * 4]);
        acc.x = fmaf(hk, w.x, acc.x);
        acc.y = fmaf(hk, w.y, acc.y);
        acc.z = fmaf(hk, w.z, acc.z);
        acc.w = fmaf(hk, w.w, acc.w);
    }
    float4 adv = *reinterpret_cast<const float4*>(&a2_dst[j4 * 4]);
    float pd = acc.x * adv.x + acc.y * adv.y + acc.z * adv.z + acc.w * adv.w;
    pd += __shfl_xor(pd, 1); pd += __shfl_xor(pd, 2);
    int gnode = n0 + node;
    if (gnode < N) {
        *reinterpret_cast<float4*>(&g2[(size_t)gnode * 16 + j4 * 4]) = acc;
        if (j4 == 0) ad2[gnode] = pd;
    }
}

// ---------------- layer-2 gather + bias + log_softmax ----------------
// one wave per dst; 64 lanes = 4 edge-slots x 16 dims; batched srcs + 2x unroll
__global__ __launch_bounds__(256) void gat2_kernel(const float* __restrict__ g2,
                                                   const float* __restrict__ a2_src,
                                                   const float* __restrict__ ad2,
                                                   const int* __restrict__ row_ptr,
                                                   const int* __restrict__ csr_src,
                                                   const float* __restrict__ b2,
                                                   float* __restrict__ out, int N) {
    int dst = blockIdx.x * 4 + (threadIdx.x >> 6);
    if (dst >= N) return;
    int lane = threadIdx.x & 63;
    int slot = lane >> 4, j = lane & 15;
    float asv = a2_src[j];
    float ad = ad2[dst];
    int start = row_ptr[dst], end = row_ptr[dst + 1];
    float acc = 0.f, ssum = 0.f;
    int i = start;
    while (i < end) {
        int nb = end - i; if (nb > 64) nb = 64;
        int sreg = (lane < nb) ? csr_src[i + lane] : 0;
        int nit = (nb + 3) >> 2;
        int k = 0;
        for (; k + 2 <= nit; k += 2) {
            int idx0 = k * 4 + slot;
            int idx1 = idx0 + 4;
            int s0 = __shfl(sreg, idx0);
            int s1 = __shfl(sreg, idx1);
            bool ok0 = idx0 < nb, ok1 = idx1 < nb;
            float v0 = ok0 ? g2[(size_t)s0 * 16 + j] : 0.f;
            float v1 = ok1 ? g2[(size_t)s1 * 16 + j] : 0.f;
            float p0 = v0 * asv, p1 = v1 * asv;
            p0 += __shfl_xor(p0, 1); p0 += __shfl_xor(p0, 2); p0 += __shfl_xor(p0, 4); p0 += __shfl_xor(p0, 8);
            p1 += __shfl_xor(p1, 1); p1 += __shfl_xor(p1, 2); p1 += __shfl_xor(p1, 4); p1 += __shfl_xor(p1, 8);
            float e0 = p0 + ad; e0 = (e0 > 0.f) ? e0 : NEG_SLOPE * e0;
            float e1 = p1 + ad; e1 = (e1 > 0.f) ? e1 : NEG_SLOPE * e1;
            float x0 = ok0 ? __expf(e0) : 0.f;
            float x1 = ok1 ? __expf(e1) : 0.f;
            acc = fmaf(x0, v0, acc); ssum += x0;
            acc = fmaf(x1, v1, acc); ssum += x1;
        }
        for (; k < nit; ++k) {
            int idx0 = k * 4 + slot;
            int s0 = __shfl(sreg, idx0);
            bool ok0 = idx0 < nb;
            float v0 = ok0 ? g2[(size_t)s0 * 16 + j] : 0.f;
            float p0 = v0 * asv;
            p0 += __shfl_xor(p0, 1); p0 += __shfl_xor(p0, 2); p0 += __shfl_xor(p0, 4); p0 += __shfl_xor(p0, 8);
            float e0 = p0 + ad; e0 = (e0 > 0.f) ? e0 : NEG_SLOPE * e0;
            float x0 = ok0 ? __expf(e0) : 0.f;
            acc = fmaf(x0, v0, acc); ssum += x0;
        }
        i += nb;
    }
    acc += __shfl_xor(acc, 16); acc += __shfl_xor(acc, 32);
    ssum += __shfl_xor(ssum, 16); ssum += __shfl_xor(ssum, 32);
    float v = acc / (ssum + EPS_F) + b2[j];
    float m = v;
    for (int off = 1; off < 16; off <<= 1) m = fmaxf(m, __shfl_xor(m, off));
    float ev = __expf(v - m);
    float se = ev;
    for (int off = 1; off < 16; off <<= 1) se += __shfl_xor(se, off);
    float ls = v - m - logf(se);
    if (lane < 16) {
        out[(size_t)dst * 16 + j] = v;
        out[(size_t)N * 16 + (size_t)dst * 16 + j] = ls;
    }
}

extern "C" void kernel_launch(void* const* d_in, const int* in_sizes, int n_in,
                              void* d_out, int out_size, void* d_ws, size_t ws_size,
                              hipStream_t stream) {
    const float* x      = (const float*)d_in[0];
    const int*   eidx   = (const int*)d_in[1];
    const float* W1     = (const float*)d_in[2];
    const float* a1_src = (const float*)d_in[3];
    const float* a1_dst = (const float*)d_in[4];
    const float* b1     = (const float*)d_in[5];
    const float* W2     = (const float*)d_in[6];
    const float* a2_src = (const float*)d_in[7];
    const float* a2_dst = (const float*)d_in[8];
    const float* b2     = (const float*)d_in[9];

    const int N = in_sizes[0] / 256;
    const int E = in_sizes[1] / 2;
    const int* esrc = eidx;
    const int* edst = eidx + E;

    char* ws = (char*)d_ws;
    size_t off = 0;
    auto alloc = [&](size_t bytes) -> void* {
        void* p = ws + off;
        off += (bytes + 255) & ~size_t(255);
        return p;
    };
    float* h1     = (float*)alloc((size_t)N * 64 * 4);
    float* ad1    = (float*)alloc((size_t)N * 8 * 4);
    float* h2     = (float*)alloc((size_t)N * 64 * 4);
    float* g2     = (float*)alloc((size_t)N * 16 * 4);
    float* ad2    = (float*)alloc((size_t)N * 4);
    int* deg      = (int*)alloc((size_t)N * 4);
    int* row_ptr  = (int*)alloc((size_t)(N + 1) * 4);
    int* cursor   = (int*)alloc((size_t)N * 4);
    int* csr_src  = (int*)alloc((size_t)E * 4);
    const int nb  = (N + 1023) / 1024;
    int* bsum     = (int*)alloc((size_t)nb * 4);

    hipMemsetAsync(deg, 0, (size_t)N * 4, stream);

    gemm1_kernel<<<(N + 63) / 64, 256, 0, stream>>>(x, W1, h1, N);
    alpha1_kernel<<<(N * 8 + 255) / 256, 256, 0, stream>>>(h1, a1_dst, ad1, N);
    degree_kernel<<<(E + 255) / 256, 256, 0, stream>>>(edst, deg, E);
    scan1_kernel<<<nb, 256, 0, stream>>>(deg, row_ptr, bsum, N);
    scan2_kernel<<<1, 64, 0, stream>>>(bsum, nb);
    scan3_kernel<<<nb, 256, 0, stream>>>(row_ptr, cursor, bsum, N, E);
    fill_kernel<<<(E + 255) / 256, 256, 0, stream>>>(esrc, edst, cursor, csr_src, E);
    gat1_kernel<<<(N + 3) / 4, 256, 0, stream>>>(h1, a1_src, ad1, row_ptr, csr_src, b1, h2, N);
    gemm2_kernel<<<(N + 63) / 64, 256, 0, stream>>>(h2, W2, a2_dst, g2, ad2, N);
    gat2_kernel<<<(N + 3) / 4, 256, 0, stream>>>(g2, a2_src, ad2, row_ptr, csr_src, b2, (float*)d_out, N);
}

// Round 3
// 248.916 us; speedup vs baseline: 1.9250x; 1.6466x over previous
//
#include <hip/hip_runtime.h>

#define NEG_SLOPE 0.2f
#define EPS_F 1e-16f

#define K_MAX 256          // max buckets (N <= 131072)
#define BCAP 10240         // per-bucket capacity (exp ~8192, >20 sigma slack)
#define CHUNK 4096         // edges per bin chunk

// ---------------- Layer 1 GEMM: h1 = x @ W1   (N x 256) @ (256 x 64) ----------------
__global__ __launch_bounds__(256) void gemm1_kernel(const float* __restrict__ x,
                                                    const float* __restrict__ W1,
                                                    float* __restrict__ h1, int N) {
    __shared__ float xst[64][68];
    __shared__ float wst[64][64];
    const int t = threadIdx.x;
    const int n0 = blockIdx.x * 64;
    const int ty = t >> 4, tx = t & 15;

    float4 acc[4];
    acc[0] = make_float4(0.f, 0.f, 0.f, 0.f);
    acc[1] = acc[0]; acc[2] = acc[0]; acc[3] = acc[0];

    for (int kc = 0; kc < 256; kc += 64) {
        #pragma unroll
        for (int ii = 0; ii < 4; ++ii) {
            int fidx = (ii * 256 + t) * 4;
            int row = fidx >> 6;
            int kk = fidx & 63;
            int grow = n0 + row;
            float4 v = make_float4(0.f, 0.f, 0.f, 0.f);
            if (grow < N) v = *reinterpret_cast<const float4*>(&x[grow * 256 + kc + kk]);
            xst[kk + 0][row] = v.x;
            xst[kk + 1][row] = v.y;
            xst[kk + 2][row] = v.z;
            xst[kk + 3][row] = v.w;
        }
        #pragma unroll
        for (int ii = 0; ii < 4; ++ii) {
            int fidx = (ii * 256 + t) * 4;
            int k = fidx >> 6;
            int c = fidx & 63;
            *reinterpret_cast<float4*>(&wst[k][c]) =
                *reinterpret_cast<const float4*>(&W1[(kc + k) * 64 + c]);
        }
        __syncthreads();
        #pragma unroll
        for (int k = 0; k < 64; ++k) {
            float4 xv = *reinterpret_cast<const float4*>(&xst[k][ty * 4]);
            float4 wv = *reinterpret_cast<const float4*>(&wst[k][tx * 4]);
            acc[0].x = fmaf(xv.x, wv.x, acc[0].x);
            acc[0].y = fmaf(xv.x, wv.y, acc[0].y);
            acc[0].z = fmaf(xv.x, wv.z, acc[0].z);
            acc[0].w = fmaf(xv.x, wv.w, acc[0].w);
            acc[1].x = fmaf(xv.y, wv.x, acc[1].x);
            acc[1].y = fmaf(xv.y, wv.y, acc[1].y);
            acc[1].z = fmaf(xv.y, wv.z, acc[1].z);
            acc[1].w = fmaf(xv.y, wv.w, acc[1].w);
            acc[2].x = fmaf(xv.z, wv.x, acc[2].x);
            acc[2].y = fmaf(xv.z, wv.y, acc[2].y);
            acc[2].z = fmaf(xv.z, wv.z, acc[2].z);
            acc[2].w = fmaf(xv.z, wv.w, acc[2].w);
            acc[3].x = fmaf(xv.w, wv.x, acc[3].x);
            acc[3].y = fmaf(xv.w, wv.y, acc[3].y);
            acc[3].z = fmaf(xv.w, wv.z, acc[3].z);
            acc[3].w = fmaf(xv.w, wv.w, acc[3].w);
        }
        __syncthreads();
    }
    #pragma unroll
    for (int i = 0; i < 4; ++i) {
        int row = n0 + ty * 4 + i;
        if (row < N) {
            *reinterpret_cast<float4*>(&h1[row * 64 + tx * 4]) = acc[i];
        }
    }
}

// ---------------- alpha1: per-node per-head dst attention dot ----------------
__global__ __launch_bounds__(256) void alpha1_kernel(const float* __restrict__ h1,
                                                     const float* __restrict__ a_dst,
                                                     float* __restrict__ ad1, int N) {
    int tid = blockIdx.x * 256 + threadIdx.x;
    int node = tid >> 3;
    int h = tid & 7;
    if (node >= N) return;
    float4 v0 = *reinterpret_cast<const float4*>(&h1[node * 64 + h * 8]);
    float4 v1 = *reinterpret_cast<const float4*>(&h1[node * 64 + h * 8 + 4]);
    float4 d0 = *reinterpret_cast<const float4*>(&a_dst[h * 8]);
    float4 d1 = *reinterpret_cast<const float4*>(&a_dst[h * 8 + 4]);
    float d = v0.x * d0.x + v0.y * d0.y + v0.z * d0.z + v0.w * d0.w
            + v1.x * d1.x + v1.y * d1.y + v1.z * d1.z + v1.w * d1.w;
    ad1[tid] = d;
}

// ---------------- phase 1: bin edges into dst-buckets (coalesced writes) ----------------
// packed word = (src << 9) | (dst & 511); bucket = dst >> 9
__global__ __launch_bounds__(256) void bin_kernel(const int* __restrict__ src,
                                                  const int* __restrict__ dst,
                                                  int* __restrict__ cursor,
                                                  unsigned* __restrict__ bins,
                                                  int E, int K) {
    __shared__ int hist[K_MAX];
    __shared__ int lbase[K_MAX];
    __shared__ int goff[K_MAX];
    __shared__ int rk[K_MAX];
    __shared__ int sc[256];
    __shared__ unsigned pk[CHUNK];
    __shared__ unsigned short bid[CHUNK];

    int t = threadIdx.x;
    int nchunks = (E + CHUNK - 1) / CHUNK;
    for (int c = blockIdx.x; c < nchunks; c += gridDim.x) {
        int e0 = c * CHUNK;
        int ne = E - e0; if (ne > CHUNK) ne = CHUNK;
        for (int j = t; j < K_MAX; j += 256) { hist[j] = 0; rk[j] = 0; }
        __syncthreads();

        unsigned pks[16];
        int bks[16];
        #pragma unroll
        for (int k = 0; k < 16; ++k) {
            int i = e0 + t + k * 256;
            if (i < e0 + ne) {
                int d = dst[i];
                int s = src[i];
                int b = d >> 9;
                pks[k] = ((unsigned)s << 9) | (unsigned)(d & 511);
                bks[k] = b;
                atomicAdd(&hist[b], 1);
            } else {
                bks[k] = -1;
            }
        }
        __syncthreads();
        // scan hist (K entries) -> lbase exclusive; reserve global space
        int hv = (t < K) ? hist[t] : 0;
        int val = hv;
        sc[t] = val; __syncthreads();
        for (int off = 1; off < 256; off <<= 1) {
            int add = (t >= off) ? sc[t - off] : 0;
            __syncthreads();
            val += add; sc[t] = val;
            __syncthreads();
        }
        if (t < K) {
            lbase[t] = val - hv;
            goff[t] = hv ? atomicAdd(&cursor[t], hv) : 0;
        }
        __syncthreads();
        // scatter into LDS ordered by bucket
        #pragma unroll
        for (int k = 0; k < 16; ++k) {
            if (bks[k] >= 0) {
                int r = atomicAdd(&rk[bks[k]], 1);
                int p = lbase[bks[k]] + r;
                pk[p] = pks[k];
                bid[p] = (unsigned short)bks[k];
            }
        }
        __syncthreads();
        // bulk coalesced write per bucket segment
        for (int j = t; j < ne; j += 256) {
            int b = bid[j];
            bins[(size_t)b * BCAP + goff[b] + (j - lbase[b])] = pk[j];
        }
        __syncthreads();
    }
}

// ---------------- tiny scan over bucket counts ----------------
__global__ void bscan_kernel(const int* __restrict__ cursor, int* __restrict__ bbase,
                             int* __restrict__ row_ptr, int K, int N, int E) {
    __shared__ int sc[256];
    int t = threadIdx.x;
    int v = (t < K) ? cursor[t] : 0;
    int val = v;
    sc[t] = val; __syncthreads();
    for (int off = 1; off < 256; off <<= 1) {
        int add = (t >= off) ? sc[t - off] : 0;
        __syncthreads();
        val += add; sc[t] = val;
        __syncthreads();
    }
    if (t < K) bbase[t] = val - v;
    if (t == 0) row_ptr[N] = E;
}

// ---------------- phase 2: per-bucket CSR build (L2-local scatter) ----------------
__global__ __launch_bounds__(256) void csr_kernel(const unsigned* __restrict__ bins,
                                                  const int* __restrict__ cursor,
                                                  const int* __restrict__ bbase,
                                                  int* __restrict__ row_ptr,
                                                  int* __restrict__ csr_src, int N) {
    __shared__ unsigned pk[BCAP];      // 40KB
    __shared__ int hist[512];
    __shared__ int ex[512];
    __shared__ int rk2[512];
    __shared__ int sc[256];
    int b = blockIdx.x;
    int t = threadIdx.x;
    int cnt = cursor[b];
    int base_g = bbase[b];
    for (int j = t; j < cnt; j += 256) pk[j] = bins[(size_t)b * BCAP + j];
    for (int j = t; j < 512; j += 256) { hist[j] = 0; rk2[j] = 0; }
    __syncthreads();
    for (int j = t; j < cnt; j += 256) atomicAdd(&hist[pk[j] & 511u], 1);
    __syncthreads();
    // scan 512 with 256 threads (pairwise)
    int h0 = hist[2 * t], h1v = hist[2 * t + 1];
    int s = h0 + h1v;
    int val = s;
    sc[t] = val; __syncthreads();
    for (int off = 1; off < 256; off <<= 1) {
        int add = (t >= off) ? sc[t - off] : 0;
        __syncthreads();
        val += add; sc[t] = val;
        __syncthreads();
    }
    int excl = val - s;
    ex[2 * t] = excl;
    ex[2 * t + 1] = excl + h0;
    __syncthreads();
    // row_ptr (coalesced)
    int nd0 = b << 9;
    for (int ld = t; ld < 512; ld += 256) {
        int d = nd0 + ld;
        if (d < N) row_ptr[d] = base_g + ex[ld];
    }
    // scatter srcs into L2-resident window
    for (int j = t; j < cnt; j += 256) {
        unsigned w = pk[j];
        int ld = (int)(w & 511u);
        int r = atomicAdd(&rk2[ld], 1);
        csr_src[base_g + ex[ld] + r] = (int)(w >> 9);
    }
}

// ---------------- layer-1 gather: predicated 8-wide ILP ----------------
__global__ __launch_bounds__(256) void gat1_kernel(const float* __restrict__ h1,
                                                   const float* __restrict__ a1_src,
                                                   const float* __restrict__ ad1,
                                                   const int* __restrict__ row_ptr,
                                                   const int* __restrict__ csr_src,
                                                   const float* __restrict__ b1,
                                                   float* __restrict__ h2, int N) {
    int dst = blockIdx.x * 4 + (threadIdx.x >> 6);
    if (dst >= N) return;
    int lane = threadIdx.x & 63;
    int h = lane >> 3;
    float asv = a1_src[lane];
    float ad = ad1[dst * 8 + h];
    int start = row_ptr[dst];
    int end = row_ptr[dst + 1];
    float acc = 0.f, ssum = 0.f;
    int i = start;
    while (i < end) {
        int nb = end - i; if (nb > 64) nb = 64;
        int sreg = (lane < nb) ? csr_src[i + lane] : 0;
        for (int k = 0; k < nb; k += 8) {
            int ss[8];
            float vv[8];
            #pragma unroll
            for (int j = 0; j < 8; ++j) ss[j] = __shfl(sreg, k + j);
            #pragma unroll
            for (int j = 0; j < 8; ++j) vv[j] = h1[(size_t)ss[j] * 64 + lane];
            #pragma unroll
            for (int j = 0; j < 8; ++j) {
                float p = vv[j] * asv;
                p += __shfl_xor(p, 1); p += __shfl_xor(p, 2); p += __shfl_xor(p, 4);
                float e = p + ad;
                e = (e > 0.f) ? e : NEG_SLOPE * e;
                float x = (k + j < nb) ? __expf(e) : 0.f;
                acc = fmaf(x, vv[j], acc);
                ssum += x;
            }
        }
        i += nb;
    }
    float out = acc / (ssum + EPS_F) + b1[lane];
    float h2v = (out > 0.f) ? out : (__expf(out) - 1.f);  // ELU
    h2[(size_t)dst * 64 + lane] = h2v;
}

// ---------------- Layer 2 GEMM: g2 = h2 @ W2  + dst dot ----------------
__global__ __launch_bounds__(256) void gemm2_kernel(const float* __restrict__ h2,
                                                    const float* __restrict__ W2,
                                                    const float* __restrict__ a2_dst,
                                                    float* __restrict__ g2,
                                                    float* __restrict__ ad2, int N) {
    __shared__ float hs[64][68];
    __shared__ float ws[1024];
    int t = threadIdx.x;
    int n0 = blockIdx.x * 64;
    *reinterpret_cast<float4*>(&ws[t * 4]) = *reinterpret_cast<const float4*>(&W2[t * 4]);
    #pragma unroll
    for (int ii = 0; ii < 4; ++ii) {
        int fidx = (ii * 256 + t) * 4;
        int row = fidx >> 6;
        int col = fidx & 63;
        float4 v = make_float4(0.f, 0.f, 0.f, 0.f);
        if (n0 + row < N) v = *reinterpret_cast<const float4*>(&h2[(size_t)(n0 + row) * 64 + col]);
        *reinterpret_cast<float4*>(&hs[row][col]) = v;
    }
    __syncthreads();
    int node = t >> 2, j4 = t & 3;
    float4 acc = make_float4(0.f, 0.f, 0.f, 0.f);
    #pragma unroll
    for (int k = 0; k < 64; ++k) {
        float hk = hs[node][k];
        float4 w = *reinterpret_cast<const float4*>(&ws[k * 16 + j4 * 4]);
        acc.x = fmaf(hk, w.x, acc.x);
        acc.y = fmaf(hk, w.y, acc.y);
        acc.z = fmaf(hk, w.z, acc.z);
        acc.w = fmaf(hk, w.w, acc.w);
    }
    float4 adv = *reinterpret_cast<const float4*>(&a2_dst[j4 * 4]);
    float pd = acc.x * adv.x + acc.y * adv.y + acc.z * adv.z + acc.w * adv.w;
    pd += __shfl_xor(pd, 1); pd += __shfl_xor(pd, 2);
    int gnode = n0 + node;
    if (gnode < N) {
        *reinterpret_cast<float4*>(&g2[(size_t)gnode * 16 + j4 * 4]) = acc;
        if (j4 == 0) ad2[gnode] = pd;
    }
}

// ---------------- layer-2 gather + bias + log_softmax: predicated 4-wide ----------------
__global__ __launch_bounds__(256) void gat2_kernel(const float* __restrict__ g2,
                                                   const float* __restrict__ a2_src,
                                                   const float* __restrict__ ad2,
                                                   const int* __restrict__ row_ptr,
                                                   const int* __restrict__ csr_src,
                                                   const float* __restrict__ b2,
                                                   float* __restrict__ out, int N) {
    int dst = blockIdx.x * 4 + (threadIdx.x >> 6);
    if (dst >= N) return;
    int lane = threadIdx.x & 63;
    int slot = lane >> 4, j = lane & 15;
    float asv = a2_src[j];
    float ad = ad2[dst];
    int start = row_ptr[dst], end = row_ptr[dst + 1];
    float acc = 0.f, ssum = 0.f;
    int i = start;
    while (i < end) {
        int nb = end - i; if (nb > 64) nb = 64;
        int sreg = (lane < nb) ? csr_src[i + lane] : 0;
        int nit = (nb + 3) >> 2;
        for (int k = 0; k < nit; k += 4) {
            int ss[4]; float vv[4]; bool ok[4];
            #pragma unroll
            for (int q = 0; q < 4; ++q) {
                int idx = (k + q) * 4 + slot;
                ss[q] = __shfl(sreg, idx);
                ok[q] = idx < nb;
            }
            #pragma unroll
            for (int q = 0; q < 4; ++q) vv[q] = ok[q] ? g2[(size_t)ss[q] * 16 + j] : 0.f;
            #pragma unroll
            for (int q = 0; q < 4; ++q) {
                float p = vv[q] * asv;
                p += __shfl_xor(p, 1); p += __shfl_xor(p, 2);
                p += __shfl_xor(p, 4); p += __shfl_xor(p, 8);
                float e = p + ad;
                e = (e > 0.f) ? e : NEG_SLOPE * e;
                float x = ok[q] ? __expf(e) : 0.f;
                acc = fmaf(x, vv[q], acc);
                ssum += x;
            }
        }
        i += nb;
    }
    acc += __shfl_xor(acc, 16); acc += __shfl_xor(acc, 32);
    ssum += __shfl_xor(ssum, 16); ssum += __shfl_xor(ssum, 32);
    float v = acc / (ssum + EPS_F) + b2[j];
    float m = v;
    for (int off = 1; off < 16; off <<= 1) m = fmaxf(m, __shfl_xor(m, off));
    float ev = __expf(v - m);
    float se = ev;
    for (int off = 1; off < 16; off <<= 1) se += __shfl_xor(se, off);
    float ls = v - m - logf(se);
    if (lane < 16) {
        out[(size_t)dst * 16 + j] = v;
        out[(size_t)N * 16 + (size_t)dst * 16 + j] = ls;
    }
}

extern "C" void kernel_launch(void* const* d_in, const int* in_sizes, int n_in,
                              void* d_out, int out_size, void* d_ws, size_t ws_size,
                              hipStream_t stream) {
    const float* x      = (const float*)d_in[0];
    const int*   eidx   = (const int*)d_in[1];
    const float* W1     = (const float*)d_in[2];
    const float* a1_src = (const float*)d_in[3];
    const float* a1_dst = (const float*)d_in[4];
    const float* b1     = (const float*)d_in[5];
    const float* W2     = (const float*)d_in[6];
    const float* a2_src = (const float*)d_in[7];
    const float* a2_dst = (const float*)d_in[8];
    const float* b2     = (const float*)d_in[9];

    const int N = in_sizes[0] / 256;
    const int E = in_sizes[1] / 2;
    const int K = (N + 511) >> 9;         // dst buckets of 512 nodes
    const int* esrc = eidx;
    const int* edst = eidx + E;

    char* ws = (char*)d_ws;
    size_t off = 0;
    auto alloc = [&](size_t bytes) -> void* {
        void* p = ws + off;
        off += (bytes + 255) & ~size_t(255);
        return p;
    };
    float* h1        = (float*)alloc((size_t)N * 64 * 4);
    float* ad1       = (float*)alloc((size_t)N * 8 * 4);
    float* h2        = (float*)alloc((size_t)N * 64 * 4);
    float* g2        = (float*)alloc((size_t)N * 16 * 4);
    float* ad2       = (float*)alloc((size_t)N * 4);
    int* row_ptr     = (int*)alloc((size_t)(N + 1) * 4);
    int* csr_src     = (int*)alloc((size_t)E * 4);
    int* cursor      = (int*)alloc((size_t)K * 4);
    int* bbase       = (int*)alloc((size_t)K * 4);
    unsigned* bins   = (unsigned*)alloc((size_t)K * BCAP * 4);

    hipMemsetAsync(cursor, 0, (size_t)K * 4, stream);

    gemm1_kernel<<<(N + 63) / 64, 256, 0, stream>>>(x, W1, h1, N);
    alpha1_kernel<<<(N * 8 + 255) / 256, 256, 0, stream>>>(h1, a1_dst, ad1, N);
    bin_kernel<<<(E + CHUNK - 1) / CHUNK, 256, 0, stream>>>(esrc, edst, cursor, bins, E, K);
    bscan_kernel<<<1, 256, 0, stream>>>(cursor, bbase, row_ptr, K, N, E);
    csr_kernel<<<K, 256, 0, stream>>>(bins, cursor, bbase, row_ptr, csr_src, N);
    gat1_kernel<<<(N + 3) / 4, 256, 0, stream>>>(h1, a1_src, ad1, row_ptr, csr_src, b1, h2, N);
    gemm2_kernel<<<(N + 63) / 64, 256, 0, stream>>>(h2, W2, a2_dst, g2, ad2, N);
    gat2_kernel<<<(N + 3) / 4, 256, 0, stream>>>(g2, a2_src, ad2, row_ptr, csr_src, b2, (float*)d_out, N);
}

// Round 4
// 243.217 us; speedup vs baseline: 1.9702x; 1.0234x over previous
//
#include <hip/hip_runtime.h>

#define NEG_SLOPE 0.2f
#define EPS_F 1e-16f

#define K_MAX 256          // max buckets (N <= 131072)
#define BCAP 10240         // per-bucket capacity
#define CHUNK 4096         // edges per bin chunk

// ---------------- Layer 1 GEMM: h1 = x @ W1   (N x 256) @ (256 x 64) ----------------
__global__ __launch_bounds__(256) void gemm1_kernel(const float* __restrict__ x,
                                                    const float* __restrict__ W1,
                                                    float* __restrict__ h1, int N) {
    __shared__ float xst[64][68];
    __shared__ float wst[64][64];
    const int t = threadIdx.x;
    const int n0 = blockIdx.x * 64;
    const int ty = t >> 4, tx = t & 15;

    float4 acc[4];
    acc[0] = make_float4(0.f, 0.f, 0.f, 0.f);
    acc[1] = acc[0]; acc[2] = acc[0]; acc[3] = acc[0];

    for (int kc = 0; kc < 256; kc += 64) {
        #pragma unroll
        for (int ii = 0; ii < 4; ++ii) {
            int fidx = (ii * 256 + t) * 4;
            int row = fidx >> 6;
            int kk = fidx & 63;
            int grow = n0 + row;
            float4 v = make_float4(0.f, 0.f, 0.f, 0.f);
            if (grow < N) v = *reinterpret_cast<const float4*>(&x[grow * 256 + kc + kk]);
            xst[kk + 0][row] = v.x;
            xst[kk + 1][row] = v.y;
            xst[kk + 2][row] = v.z;
            xst[kk + 3][row] = v.w;
        }
        #pragma unroll
        for (int ii = 0; ii < 4; ++ii) {
            int fidx = (ii * 256 + t) * 4;
            int k = fidx >> 6;
            int c = fidx & 63;
            *reinterpret_cast<float4*>(&wst[k][c]) =
                *reinterpret_cast<const float4*>(&W1[(kc + k) * 64 + c]);
        }
        __syncthreads();
        #pragma unroll
        for (int k = 0; k < 64; ++k) {
            float4 xv = *reinterpret_cast<const float4*>(&xst[k][ty * 4]);
            float4 wv = *reinterpret_cast<const float4*>(&wst[k][tx * 4]);
            acc[0].x = fmaf(xv.x, wv.x, acc[0].x);
            acc[0].y = fmaf(xv.x, wv.y, acc[0].y);
            acc[0].z = fmaf(xv.x, wv.z, acc[0].z);
            acc[0].w = fmaf(xv.x, wv.w, acc[0].w);
            acc[1].x = fmaf(xv.y, wv.x, acc[1].x);
            acc[1].y = fmaf(xv.y, wv.y, acc[1].y);
            acc[1].z = fmaf(xv.y, wv.z, acc[1].z);
            acc[1].w = fmaf(xv.y, wv.w, acc[1].w);
            acc[2].x = fmaf(xv.z, wv.x, acc[2].x);
            acc[2].y = fmaf(xv.z, wv.y, acc[2].y);
            acc[2].z = fmaf(xv.z, wv.z, acc[2].z);
            acc[2].w = fmaf(xv.z, wv.w, acc[2].w);
            acc[3].x = fmaf(xv.w, wv.x, acc[3].x);
            acc[3].y = fmaf(xv.w, wv.y, acc[3].y);
            acc[3].z = fmaf(xv.w, wv.z, acc[3].z);
            acc[3].w = fmaf(xv.w, wv.w, acc[3].w);
        }
        __syncthreads();
    }
    #pragma unroll
    for (int i = 0; i < 4; ++i) {
        int row = n0 + ty * 4 + i;
        if (row < N) {
            *reinterpret_cast<float4*>(&h1[row * 64 + tx * 4]) = acc[i];
        }
    }
}

// ---------------- alpha1: per-node per-head src+dst attention dots ----------------
__global__ __launch_bounds__(256) void alpha1_kernel(const float* __restrict__ h1,
                                                     const float* __restrict__ a_src,
                                                     const float* __restrict__ a_dst,
                                                     float* __restrict__ as1,
                                                     float* __restrict__ ad1, int N) {
    int tid = blockIdx.x * 256 + threadIdx.x;
    int node = tid >> 3;
    int h = tid & 7;
    if (node >= N) return;
    float4 v0 = *reinterpret_cast<const float4*>(&h1[node * 64 + h * 8]);
    float4 v1 = *reinterpret_cast<const float4*>(&h1[node * 64 + h * 8 + 4]);
    float4 s0 = *reinterpret_cast<const float4*>(&a_src[h * 8]);
    float4 s1 = *reinterpret_cast<const float4*>(&a_src[h * 8 + 4]);
    float4 d0 = *reinterpret_cast<const float4*>(&a_dst[h * 8]);
    float4 d1 = *reinterpret_cast<const float4*>(&a_dst[h * 8 + 4]);
    float s = v0.x * s0.x + v0.y * s0.y + v0.z * s0.z + v0.w * s0.w
            + v1.x * s1.x + v1.y * s1.y + v1.z * s1.z + v1.w * s1.w;
    float d = v0.x * d0.x + v0.y * d0.y + v0.z * d0.z + v0.w * d0.w
            + v1.x * d1.x + v1.y * d1.y + v1.z * d1.z + v1.w * d1.w;
    as1[tid] = s;
    ad1[tid] = d;
}

// ---------------- phase 1: bin edges into dst-buckets (coalesced writes) ----------------
__global__ __launch_bounds__(256) void bin_kernel(const int* __restrict__ src,
                                                  const int* __restrict__ dst,
                                                  int* __restrict__ cursor,
                                                  unsigned* __restrict__ bins,
                                                  int E, int K) {
    __shared__ int hist[K_MAX];
    __shared__ int lbase[K_MAX];
    __shared__ int goff[K_MAX];
    __shared__ int rk[K_MAX];
    __shared__ int sc[256];
    __shared__ unsigned pk[CHUNK];
    __shared__ unsigned short bid[CHUNK];

    int t = threadIdx.x;
    int nchunks = (E + CHUNK - 1) / CHUNK;
    for (int c = blockIdx.x; c < nchunks; c += gridDim.x) {
        int e0 = c * CHUNK;
        int ne = E - e0; if (ne > CHUNK) ne = CHUNK;
        for (int j = t; j < K_MAX; j += 256) { hist[j] = 0; rk[j] = 0; }
        __syncthreads();

        unsigned pks[16];
        int bks[16];
        #pragma unroll
        for (int k = 0; k < 16; ++k) {
            int i = e0 + t + k * 256;
            if (i < e0 + ne) {
                int d = dst[i];
                int s = src[i];
                int b = d >> 9;
                pks[k] = ((unsigned)s << 9) | (unsigned)(d & 511);
                bks[k] = b;
                atomicAdd(&hist[b], 1);
            } else {
                bks[k] = -1;
            }
        }
        __syncthreads();
        int hv = (t < K) ? hist[t] : 0;
        int val = hv;
        sc[t] = val; __syncthreads();
        for (int off = 1; off < 256; off <<= 1) {
            int add = (t >= off) ? sc[t - off] : 0;
            __syncthreads();
            val += add; sc[t] = val;
            __syncthreads();
        }
        if (t < K) {
            lbase[t] = val - hv;
            goff[t] = hv ? atomicAdd(&cursor[t], hv) : 0;
        }
        __syncthreads();
        #pragma unroll
        for (int k = 0; k < 16; ++k) {
            if (bks[k] >= 0) {
                int r = atomicAdd(&rk[bks[k]], 1);
                int p = lbase[bks[k]] + r;
                pk[p] = pks[k];
                bid[p] = (unsigned short)bks[k];
            }
        }
        __syncthreads();
        for (int j = t; j < ne; j += 256) {
            int b = bid[j];
            bins[(size_t)b * BCAP + goff[b] + (j - lbase[b])] = pk[j];
        }
        __syncthreads();
    }
}

// ---------------- tiny scan over bucket counts ----------------
__global__ void bscan_kernel(const int* __restrict__ cursor, int* __restrict__ bbase,
                             int* __restrict__ row_ptr, int K, int N, int E) {
    __shared__ int sc[256];
    int t = threadIdx.x;
    int v = (t < K) ? cursor[t] : 0;
    int val = v;
    sc[t] = val; __syncthreads();
    for (int off = 1; off < 256; off <<= 1) {
        int add = (t >= off) ? sc[t - off] : 0;
        __syncthreads();
        val += add; sc[t] = val;
        __syncthreads();
    }
    if (t < K) bbase[t] = val - v;
    if (t == 0) row_ptr[N] = E;
}

// ---------------- phase 2: per-bucket CSR build (L2-local scatter) ----------------
__global__ __launch_bounds__(256) void csr_kernel(const unsigned* __restrict__ bins,
                                                  const int* __restrict__ cursor,
                                                  const int* __restrict__ bbase,
                                                  int* __restrict__ row_ptr,
                                                  int* __restrict__ csr_src, int N) {
    __shared__ unsigned pk[BCAP];
    __shared__ int hist[512];
    __shared__ int ex[512];
    __shared__ int rk2[512];
    __shared__ int sc[256];
    int b = blockIdx.x;
    int t = threadIdx.x;
    int cnt = cursor[b];
    int base_g = bbase[b];
    for (int j = t; j < cnt; j += 256) pk[j] = bins[(size_t)b * BCAP + j];
    for (int j = t; j < 512; j += 256) { hist[j] = 0; rk2[j] = 0; }
    __syncthreads();
    for (int j = t; j < cnt; j += 256) atomicAdd(&hist[pk[j] & 511u], 1);
    __syncthreads();
    int h0 = hist[2 * t], h1v = hist[2 * t + 1];
    int s = h0 + h1v;
    int val = s;
    sc[t] = val; __syncthreads();
    for (int off = 1; off < 256; off <<= 1) {
        int add = (t >= off) ? sc[t - off] : 0;
        __syncthreads();
        val += add; sc[t] = val;
        __syncthreads();
    }
    int excl = val - s;
    ex[2 * t] = excl;
    ex[2 * t + 1] = excl + h0;
    __syncthreads();
    int nd0 = b << 9;
    for (int ld = t; ld < 512; ld += 256) {
        int d = nd0 + ld;
        if (d < N) row_ptr[d] = base_g + ex[ld];
    }
    for (int j = t; j < cnt; j += 256) {
        unsigned w = pk[j];
        int ld = (int)(w & 511u);
        int r = atomicAdd(&rk2[ld], 1);
        csr_src[base_g + ex[ld] + r] = (int)(w >> 9);
    }
}

// ---------------- layer-1 gather: readlane broadcast + as1 gather, no inner shuffles ----------------
__global__ __launch_bounds__(256) void gat1_kernel(const float* __restrict__ h1,
                                                   const float* __restrict__ as1,
                                                   const float* __restrict__ ad1,
                                                   const int* __restrict__ row_ptr,
                                                   const int* __restrict__ csr_src,
                                                   const float* __restrict__ b1,
                                                   float* __restrict__ h2, int N) {
    int dst = blockIdx.x * 4 + (threadIdx.x >> 6);
    if (dst >= N) return;
    int lane = threadIdx.x & 63;
    int h = lane >> 3;
    float ad = ad1[dst * 8 + h];
    int start = row_ptr[dst];
    int end = row_ptr[dst + 1];
    float acc = 0.f, ssum = 0.f;
    int i = start;
    while (i < end) {
        int nb = end - i; if (nb > 64) nb = 64;
        int sreg = (lane < nb) ? csr_src[i + lane] : 0;
        int nb8 = nb & ~7;
        int k = 0;
        for (; k < nb8; k += 8) {
            int ss[8]; float vv[8], aa[8];
            #pragma unroll
            for (int j = 0; j < 8; ++j) ss[j] = __builtin_amdgcn_readlane(sreg, k + j);
            #pragma unroll
            for (int j = 0; j < 8; ++j) {
                vv[j] = h1[(size_t)ss[j] * 64 + lane];
                aa[j] = as1[ss[j] * 8 + h];
            }
            #pragma unroll
            for (int j = 0; j < 8; ++j) {
                float e = aa[j] + ad;
                e = fmaxf(e, NEG_SLOPE * e);          // leaky_relu
                float x = __expf(e);
                acc = fmaf(x, vv[j], acc);
                ssum += x;
            }
        }
        for (; k < nb; ++k) {
            int s0 = __builtin_amdgcn_readlane(sreg, k);
            float v = h1[(size_t)s0 * 64 + lane];
            float a = as1[s0 * 8 + h];
            float e = a + ad;
            e = fmaxf(e, NEG_SLOPE * e);
            float x = __expf(e);
            acc = fmaf(x, v, acc);
            ssum += x;
        }
        i += nb;
    }
    float out = acc / (ssum + EPS_F) + b1[lane];
    float h2v = (out > 0.f) ? out : (__expf(out) - 1.f);  // ELU
    h2[(size_t)dst * 64 + lane] = h2v;
}

// ---------------- Layer 2 GEMM: g2 = h2 @ W2  + src/dst dots ----------------
__global__ __launch_bounds__(256) void gemm2_kernel(const float* __restrict__ h2,
                                                    const float* __restrict__ W2,
                                                    const float* __restrict__ a2_src,
                                                    const float* __restrict__ a2_dst,
                                                    float* __restrict__ g2,
                                                    float* __restrict__ as2,
                                                    float* __restrict__ ad2, int N) {
    __shared__ float hs[64][68];
    __shared__ float ws[1024];
    int t = threadIdx.x;
    int n0 = blockIdx.x * 64;
    *reinterpret_cast<float4*>(&ws[t * 4]) = *reinterpret_cast<const float4*>(&W2[t * 4]);
    #pragma unroll
    for (int ii = 0; ii < 4; ++ii) {
        int fidx = (ii * 256 + t) * 4;
        int row = fidx >> 6;
        int col = fidx & 63;
        float4 v = make_float4(0.f, 0.f, 0.f, 0.f);
        if (n0 + row < N) v = *reinterpret_cast<const float4*>(&h2[(size_t)(n0 + row) * 64 + col]);
        *reinterpret_cast<float4*>(&hs[row][col]) = v;
    }
    __syncthreads();
    int node = t >> 2, j4 = t & 3;
    float4 acc = make_float4(0.f, 0.f, 0.f, 0.f);
    #pragma unroll
    for (int k = 0; k < 64; ++k) {
        float hk = hs[node][k];
        float4 w = *reinterpret_cast<const float4*>(&ws[k * 16 + j4 * 4]);
        acc.x = fmaf(hk, w.x, acc.x);
        acc.y = fmaf(hk, w.y, acc.y);
        acc.z = fmaf(hk, w.z, acc.z);
        acc.w = fmaf(hk, w.w, acc.w);
    }
    float4 asv = *reinterpret_cast<const float4*>(&a2_src[j4 * 4]);
    float4 adv = *reinterpret_cast<const float4*>(&a2_dst[j4 * 4]);
    float ps = acc.x * asv.x + acc.y * asv.y + acc.z * asv.z + acc.w * asv.w;
    float pd = acc.x * adv.x + acc.y * adv.y + acc.z * adv.z + acc.w * adv.w;
    ps += __shfl_xor(ps, 1); ps += __shfl_xor(ps, 2);
    pd += __shfl_xor(pd, 1); pd += __shfl_xor(pd, 2);
    int gnode = n0 + node;
    if (gnode < N) {
        *reinterpret_cast<float4*>(&g2[(size_t)gnode * 16 + j4 * 4]) = acc;
        if (j4 == 0) { as2[gnode] = ps; ad2[gnode] = pd; }
    }
}

// ---------------- layer-2 gather + bias + log_softmax ----------------
// lanes = 4 slots x 16 dims; direct per-slot index loads, as2 gather, 2-deep unroll
__global__ __launch_bounds__(256) void gat2_kernel(const float* __restrict__ g2,
                                                   const float* __restrict__ as2,
                                                   const float* __restrict__ ad2,
                                                   const int* __restrict__ row_ptr,
                                                   const int* __restrict__ csr_src,
                                                   const float* __restrict__ b2,
                                                   float* __restrict__ out, int N) {
    int dst = blockIdx.x * 4 + (threadIdx.x >> 6);
    if (dst >= N) return;
    int lane = threadIdx.x & 63;
    int slot = lane >> 4, j = lane & 15;
    float ad = ad2[dst];
    int start = row_ptr[dst], end = row_ptr[dst + 1];
    float acc = 0.f, ssum = 0.f;
    for (int k = start + slot; k < end; k += 8) {
        int s0 = csr_src[k];
        bool ok1 = (k + 4) < end;
        int s1 = ok1 ? csr_src[k + 4] : s0;
        float v0 = g2[(size_t)s0 * 16 + j];
        float a0 = as2[s0];
        float v1 = g2[(size_t)s1 * 16 + j];
        float a1 = as2[s1];
        float e0 = a0 + ad; e0 = fmaxf(e0, NEG_SLOPE * e0);
        float e1 = a1 + ad; e1 = fmaxf(e1, NEG_SLOPE * e1);
        float x0 = __expf(e0);
        float x1 = ok1 ? __expf(e1) : 0.f;
        acc = fmaf(x0, v0, acc); ssum += x0;
        acc = fmaf(x1, v1, acc); ssum += x1;
    }
    acc += __shfl_xor(acc, 16); acc += __shfl_xor(acc, 32);
    ssum += __shfl_xor(ssum, 16); ssum += __shfl_xor(ssum, 32);
    float v = acc / (ssum + EPS_F) + b2[j];
    float m = v;
    for (int off = 1; off < 16; off <<= 1) m = fmaxf(m, __shfl_xor(m, off));
    float ev = __expf(v - m);
    float se = ev;
    for (int off = 1; off < 16; off <<= 1) se += __shfl_xor(se, off);
    float ls = v - m - logf(se);
    if (lane < 16) {
        out[(size_t)dst * 16 + j] = v;
        out[(size_t)N * 16 + (size_t)dst * 16 + j] = ls;
    }
}

extern "C" void kernel_launch(void* const* d_in, const int* in_sizes, int n_in,
                              void* d_out, int out_size, void* d_ws, size_t ws_size,
                              hipStream_t stream) {
    const float* x      = (const float*)d_in[0];
    const int*   eidx   = (const int*)d_in[1];
    const float* W1     = (const float*)d_in[2];
    const float* a1_src = (const float*)d_in[3];
    const float* a1_dst = (const float*)d_in[4];
    const float* b1     = (const float*)d_in[5];
    const float* W2     = (const float*)d_in[6];
    const float* a2_src = (const float*)d_in[7];
    const float* a2_dst = (const float*)d_in[8];
    const float* b2     = (const float*)d_in[9];

    const int N = in_sizes[0] / 256;
    const int E = in_sizes[1] / 2;
    const int K = (N + 511) >> 9;
    const int* esrc = eidx;
    const int* edst = eidx + E;

    char* ws = (char*)d_ws;
    size_t off = 0;
    auto alloc = [&](size_t bytes) -> void* {
        void* p = ws + off;
        off += (bytes + 255) & ~size_t(255);
        return p;
    };
    float* h1        = (float*)alloc((size_t)N * 64 * 4);
    float* as1       = (float*)alloc((size_t)N * 8 * 4);
    float* ad1       = (float*)alloc((size_t)N * 8 * 4);
    float* h2        = (float*)alloc((size_t)N * 64 * 4);
    float* g2        = (float*)alloc((size_t)N * 16 * 4);
    float* as2       = (float*)alloc((size_t)N * 4);
    float* ad2       = (float*)alloc((size_t)N * 4);
    int* row_ptr     = (int*)alloc((size_t)(N + 1) * 4);
    int* csr_src     = (int*)alloc((size_t)E * 4);
    int* cursor      = (int*)alloc((size_t)K * 4);
    int* bbase       = (int*)alloc((size_t)K * 4);
    unsigned* bins   = (unsigned*)alloc((size_t)K * BCAP * 4);

    hipMemsetAsync(cursor, 0, (size_t)K * 4, stream);

    gemm1_kernel<<<(N + 63) / 64, 256, 0, stream>>>(x, W1, h1, N);
    alpha1_kernel<<<(N * 8 + 255) / 256, 256, 0, stream>>>(h1, a1_src, a1_dst, as1, ad1, N);
    bin_kernel<<<(E + CHUNK - 1) / CHUNK, 256, 0, stream>>>(esrc, edst, cursor, bins, E, K);
    bscan_kernel<<<1, 256, 0, stream>>>(cursor, bbase, row_ptr, K, N, E);
    csr_kernel<<<K, 256, 0, stream>>>(bins, cursor, bbase, row_ptr, csr_src, N);
    gat1_kernel<<<(N + 3) / 4, 256, 0, stream>>>(h1, as1, ad1, row_ptr, csr_src, b1, h2, N);
    gemm2_kernel<<<(N + 63) / 64, 256, 0, stream>>>(h2, W2, a2_src, a2_dst, g2, as2, ad2, N);
    gat2_kernel<<<(N + 3) / 4, 256, 0, stream>>>(g2, as2, ad2, row_ptr, csr_src, b2, (float*)d_out, N);
}

// Round 5
// 199.630 us; speedup vs baseline: 2.4003x; 1.2183x over previous
//
#include <hip/hip_runtime.h>

#define NEG_SLOPE 0.2f
#define EPS_F 1e-16f

#define K_MAX 256          // max buckets (N <= 131072)
#define BCAP 10240         // per-bucket capacity
#define CHUNK 4096         // edges per bin chunk

typedef unsigned short u16;

// round-to-nearest-even f32 -> bf16 (finite inputs)
static __device__ __forceinline__ u16 f2bf(float f) {
    unsigned u = __float_as_uint(f);
    unsigned r = (u + 0x7fffu + ((u >> 16) & 1u)) >> 16;
    return (u16)r;
}

// ---------------- Layer 1 GEMM: h1b = bf16(x @ W1), + as1/ad1 epilogue ----------------
__global__ __launch_bounds__(256) void gemm1_kernel(const float* __restrict__ x,
                                                    const float* __restrict__ W1,
                                                    const float* __restrict__ a1_src,
                                                    const float* __restrict__ a1_dst,
                                                    u16* __restrict__ h1b,
                                                    float* __restrict__ as1,
                                                    float* __restrict__ ad1, int N) {
    __shared__ float xst[64][68];
    __shared__ float wst[64][64];
    const int t = threadIdx.x;
    const int n0 = blockIdx.x * 64;
    const int ty = t >> 4, tx = t & 15;

    float4 acc[4];
    acc[0] = make_float4(0.f, 0.f, 0.f, 0.f);
    acc[1] = acc[0]; acc[2] = acc[0]; acc[3] = acc[0];

    for (int kc = 0; kc < 256; kc += 64) {
        #pragma unroll
        for (int ii = 0; ii < 4; ++ii) {
            int fidx = (ii * 256 + t) * 4;
            int row = fidx >> 6;
            int kk = fidx & 63;
            int grow = n0 + row;
            float4 v = make_float4(0.f, 0.f, 0.f, 0.f);
            if (grow < N) v = *reinterpret_cast<const float4*>(&x[grow * 256 + kc + kk]);
            xst[kk + 0][row] = v.x;
            xst[kk + 1][row] = v.y;
            xst[kk + 2][row] = v.z;
            xst[kk + 3][row] = v.w;
        }
        #pragma unroll
        for (int ii = 0; ii < 4; ++ii) {
            int fidx = (ii * 256 + t) * 4;
            int k = fidx >> 6;
            int c = fidx & 63;
            *reinterpret_cast<float4*>(&wst[k][c]) =
                *reinterpret_cast<const float4*>(&W1[(kc + k) * 64 + c]);
        }
        __syncthreads();
        #pragma unroll
        for (int k = 0; k < 64; ++k) {
            float4 xv = *reinterpret_cast<const float4*>(&xst[k][ty * 4]);
            float4 wv = *reinterpret_cast<const float4*>(&wst[k][tx * 4]);
            acc[0].x = fmaf(xv.x, wv.x, acc[0].x);
            acc[0].y = fmaf(xv.x, wv.y, acc[0].y);
            acc[0].z = fmaf(xv.x, wv.z, acc[0].z);
            acc[0].w = fmaf(xv.x, wv.w, acc[0].w);
            acc[1].x = fmaf(xv.y, wv.x, acc[1].x);
            acc[1].y = fmaf(xv.y, wv.y, acc[1].y);
            acc[1].z = fmaf(xv.y, wv.z, acc[1].z);
            acc[1].w = fmaf(xv.y, wv.w, acc[1].w);
            acc[2].x = fmaf(xv.z, wv.x, acc[2].x);
            acc[2].y = fmaf(xv.z, wv.y, acc[2].y);
            acc[2].z = fmaf(xv.z, wv.z, acc[2].z);
            acc[2].w = fmaf(xv.z, wv.w, acc[2].w);
            acc[3].x = fmaf(xv.w, wv.x, acc[3].x);
            acc[3].y = fmaf(xv.w, wv.y, acc[3].y);
            acc[3].z = fmaf(xv.w, wv.z, acc[3].z);
            acc[3].w = fmaf(xv.w, wv.w, acc[3].w);
        }
        __syncthreads();
    }
    // epilogue: bf16 store + per-head attention dots (cols tx*4..tx*4+3 are in head tx>>1)
    float4 av = *reinterpret_cast<const float4*>(&a1_src[tx * 4]);
    float4 dv = *reinterpret_cast<const float4*>(&a1_dst[tx * 4]);
    #pragma unroll
    for (int i = 0; i < 4; ++i) {
        int row = n0 + ty * 4 + i;
        float ps = acc[i].x * av.x + acc[i].y * av.y + acc[i].z * av.z + acc[i].w * av.w;
        float pd = acc[i].x * dv.x + acc[i].y * dv.y + acc[i].z * dv.z + acc[i].w * dv.w;
        ps += __shfl_xor(ps, 1);
        pd += __shfl_xor(pd, 1);
        if (row < N) {
            ushort4 p;
            p.x = f2bf(acc[i].x); p.y = f2bf(acc[i].y);
            p.z = f2bf(acc[i].z); p.w = f2bf(acc[i].w);
            *reinterpret_cast<ushort4*>(&h1b[(size_t)row * 64 + tx * 4]) = p;
            if ((tx & 1) == 0) {
                as1[row * 8 + (tx >> 1)] = ps;
                ad1[row * 8 + (tx >> 1)] = pd;
            }
        }
    }
}

// ---------------- phase 1: bin edges into dst-buckets (coalesced writes) ----------------
__global__ __launch_bounds__(256) void bin_kernel(const int* __restrict__ src,
                                                  const int* __restrict__ dst,
                                                  int* __restrict__ cursor,
                                                  unsigned* __restrict__ bins,
                                                  int E, int K) {
    __shared__ int hist[K_MAX];
    __shared__ int lbase[K_MAX];
    __shared__ int goff[K_MAX];
    __shared__ int rk[K_MAX];
    __shared__ int sc[256];
    __shared__ unsigned pk[CHUNK];
    __shared__ unsigned short bid[CHUNK];

    int t = threadIdx.x;
    int nchunks = (E + CHUNK - 1) / CHUNK;
    for (int c = blockIdx.x; c < nchunks; c += gridDim.x) {
        int e0 = c * CHUNK;
        int ne = E - e0; if (ne > CHUNK) ne = CHUNK;
        for (int j = t; j < K_MAX; j += 256) { hist[j] = 0; rk[j] = 0; }
        __syncthreads();

        unsigned pks[16];
        int bks[16];
        #pragma unroll
        for (int k = 0; k < 16; ++k) {
            int i = e0 + t + k * 256;
            if (i < e0 + ne) {
                int d = dst[i];
                int s = src[i];
                int b = d >> 9;
                pks[k] = ((unsigned)s << 9) | (unsigned)(d & 511);
                bks[k] = b;
                atomicAdd(&hist[b], 1);
            } else {
                bks[k] = -1;
            }
        }
        __syncthreads();
        int hv = (t < K) ? hist[t] : 0;
        int val = hv;
        sc[t] = val; __syncthreads();
        for (int off = 1; off < 256; off <<= 1) {
            int add = (t >= off) ? sc[t - off] : 0;
            __syncthreads();
            val += add; sc[t] = val;
            __syncthreads();
        }
        if (t < K) {
            lbase[t] = val - hv;
            goff[t] = hv ? atomicAdd(&cursor[t], hv) : 0;
        }
        __syncthreads();
        #pragma unroll
        for (int k = 0; k < 16; ++k) {
            if (bks[k] >= 0) {
                int r = atomicAdd(&rk[bks[k]], 1);
                int p = lbase[bks[k]] + r;
                pk[p] = pks[k];
                bid[p] = (unsigned short)bks[k];
            }
        }
        __syncthreads();
        for (int j = t; j < ne; j += 256) {
            int b = bid[j];
            bins[(size_t)b * BCAP + goff[b] + (j - lbase[b])] = pk[j];
        }
        __syncthreads();
    }
}

// ---------------- phase 2: per-bucket CSR build (integrated bucket scan) ----------------
__global__ __launch_bounds__(256) void csr_kernel(const unsigned* __restrict__ bins,
                                                  const int* __restrict__ cursor,
                                                  int* __restrict__ row_ptr,
                                                  int* __restrict__ csr_src,
                                                  int N, int K, int E) {
    __shared__ unsigned pk[BCAP];
    __shared__ int hist[512];
    __shared__ int ex[512];
    __shared__ int rk2[512];
    __shared__ int sc[256];
    __shared__ int bb[256];
    int b = blockIdx.x;
    int t = threadIdx.x;

    // block-local scan of bucket counts -> global base of bucket b
    int cv = (t < K) ? cursor[t] : 0;
    int val = cv;
    sc[t] = val; __syncthreads();
    for (int off = 1; off < 256; off <<= 1) {
        int add = (t >= off) ? sc[t - off] : 0;
        __syncthreads();
        val += add; sc[t] = val;
        __syncthreads();
    }
    bb[t] = val;
    __syncthreads();
    int base_g = (b == 0) ? 0 : bb[b - 1];
    int cnt = cursor[b];
    if (b == K - 1 && t == 0) row_ptr[N] = E;
    __syncthreads();

    for (int j = t; j < cnt; j += 256) pk[j] = bins[(size_t)b * BCAP + j];
    for (int j = t; j < 512; j += 256) { hist[j] = 0; rk2[j] = 0; }
    __syncthreads();
    for (int j = t; j < cnt; j += 256) atomicAdd(&hist[pk[j] & 511u], 1);
    __syncthreads();
    int h0 = hist[2 * t], h1v = hist[2 * t + 1];
    int s = h0 + h1v;
    int v2 = s;
    sc[t] = v2; __syncthreads();
    for (int off = 1; off < 256; off <<= 1) {
        int add = (t >= off) ? sc[t - off] : 0;
        __syncthreads();
        v2 += add; sc[t] = v2;
        __syncthreads();
    }
    int excl = v2 - s;
    ex[2 * t] = excl;
    ex[2 * t + 1] = excl + h0;
    __syncthreads();
    int nd0 = b << 9;
    for (int ld = t; ld < 512; ld += 256) {
        int d = nd0 + ld;
        if (d < N) row_ptr[d] = base_g + ex[ld];
    }
    for (int j = t; j < cnt; j += 256) {
        unsigned w = pk[j];
        int ld = (int)(w & 511u);
        int r = atomicAdd(&rk2[ld], 1);
        csr_src[base_g + ex[ld] + r] = (int)(w >> 9);
    }
}

// ---------------- layer-1 gather: bf16 rows, 2 edges per wave-iteration ----------------
// lanes: half = lane>>5 selects even/odd edge; d2 = lane&31 -> dims 2*d2,2*d2+1; head = d2>>2
__global__ __launch_bounds__(256) void gat1_kernel(const u16* __restrict__ h1b,
                                                   const float* __restrict__ as1,
                                                   const float* __restrict__ ad1,
                                                   const int* __restrict__ row_ptr,
                                                   const int* __restrict__ csr_src,
                                                   const float* __restrict__ b1,
                                                   float* __restrict__ h2, int N) {
    int dst = blockIdx.x * 4 + (threadIdx.x >> 6);
    if (dst >= N) return;
    int lane = threadIdx.x & 63;
    int half = lane >> 5;
    int d2 = lane & 31;
    int h = d2 >> 2;
    float ad = ad1[dst * 8 + h];
    int start = row_ptr[dst], end = row_ptr[dst + 1];
    float acc0 = 0.f, acc1 = 0.f, ssum = 0.f;
    int i = start;
    while (i < end) {
        int nb = end - i; if (nb > 64) nb = 64;
        int sreg = (lane < nb) ? csr_src[i + lane] : 0;
        int npair = nb >> 1;
        int np4 = npair & ~3;
        int kp = 0;
        for (; kp < np4; kp += 4) {
            int sv[4]; unsigned w[4]; float av[4];
            #pragma unroll
            for (int q = 0; q < 4; ++q) {
                int slo = __builtin_amdgcn_readlane(sreg, 2 * (kp + q));
                int shi = __builtin_amdgcn_readlane(sreg, 2 * (kp + q) + 1);
                sv[q] = half ? shi : slo;
            }
            #pragma unroll
            for (int q = 0; q < 4; ++q) {
                w[q] = *reinterpret_cast<const unsigned*>(&h1b[(size_t)sv[q] * 64 + d2 * 2]);
                av[q] = as1[sv[q] * 8 + h];
            }
            #pragma unroll
            for (int q = 0; q < 4; ++q) {
                float e = av[q] + ad;
                e = fmaxf(e, NEG_SLOPE * e);
                float x = __expf(e);
                acc0 = fmaf(x, __uint_as_float(w[q] << 16), acc0);
                acc1 = fmaf(x, __uint_as_float(w[q] & 0xffff0000u), acc1);
                ssum += x;
            }
        }
        for (; kp < npair; ++kp) {
            int slo = __builtin_amdgcn_readlane(sreg, 2 * kp);
            int shi = __builtin_amdgcn_readlane(sreg, 2 * kp + 1);
            int sv = half ? shi : slo;
            unsigned w = *reinterpret_cast<const unsigned*>(&h1b[(size_t)sv * 64 + d2 * 2]);
            float a = as1[sv * 8 + h];
            float e = a + ad;
            e = fmaxf(e, NEG_SLOPE * e);
            float x = __expf(e);
            acc0 = fmaf(x, __uint_as_float(w << 16), acc0);
            acc1 = fmaf(x, __uint_as_float(w & 0xffff0000u), acc1);
            ssum += x;
        }
        if (nb & 1) {
            int sv = __builtin_amdgcn_readlane(sreg, nb - 1);
            unsigned w = *reinterpret_cast<const unsigned*>(&h1b[(size_t)sv * 64 + d2 * 2]);
            float a = as1[sv * 8 + h];
            float e = a + ad;
            e = fmaxf(e, NEG_SLOPE * e);
            float x = half ? 0.f : __expf(e);
            acc0 = fmaf(x, __uint_as_float(w << 16), acc0);
            acc1 = fmaf(x, __uint_as_float(w & 0xffff0000u), acc1);
            ssum += x;
        }
        i += nb;
    }
    acc0 += __shfl_xor(acc0, 32);
    acc1 += __shfl_xor(acc1, 32);
    ssum += __shfl_xor(ssum, 32);
    if (half == 0) {
        float2 bb = *reinterpret_cast<const float2*>(&b1[d2 * 2]);
        float inv = 1.f / (ssum + EPS_F);
        float o0 = acc0 * inv + bb.x;
        float o1 = acc1 * inv + bb.y;
        o0 = (o0 > 0.f) ? o0 : (__expf(o0) - 1.f);   // ELU
        o1 = (o1 > 0.f) ? o1 : (__expf(o1) - 1.f);
        *reinterpret_cast<float2*>(&h2[(size_t)dst * 64 + d2 * 2]) = make_float2(o0, o1);
    }
}

// ---------------- Layer 2 GEMM: g2b = bf16(h2 @ W2), + src/dst dots ----------------
__global__ __launch_bounds__(256) void gemm2_kernel(const float* __restrict__ h2,
                                                    const float* __restrict__ W2,
                                                    const float* __restrict__ a2_src,
                                                    const float* __restrict__ a2_dst,
                                                    u16* __restrict__ g2b,
                                                    float* __restrict__ as2,
                                                    float* __restrict__ ad2, int N) {
    __shared__ float hs[64][68];
    __shared__ float ws[1024];
    int t = threadIdx.x;
    int n0 = blockIdx.x * 64;
    *reinterpret_cast<float4*>(&ws[t * 4]) = *reinterpret_cast<const float4*>(&W2[t * 4]);
    #pragma unroll
    for (int ii = 0; ii < 4; ++ii) {
        int fidx = (ii * 256 + t) * 4;
        int row = fidx >> 6;
        int col = fidx & 63;
        float4 v = make_float4(0.f, 0.f, 0.f, 0.f);
        if (n0 + row < N) v = *reinterpret_cast<const float4*>(&h2[(size_t)(n0 + row) * 64 + col]);
        *reinterpret_cast<float4*>(&hs[row][col]) = v;
    }
    __syncthreads();
    int node = t >> 2, j4 = t & 3;
    float4 acc = make_float4(0.f, 0.f, 0.f, 0.f);
    #pragma unroll
    for (int k = 0; k < 64; ++k) {
        float hk = hs[node][k];
        float4 w = *reinterpret_cast<const float4*>(&ws[k * 16 + j4 * 4]);
        acc.x = fmaf(hk, w.x, acc.x);
        acc.y = fmaf(hk, w.y, acc.y);
        acc.z = fmaf(hk, w.z, acc.z);
        acc.w = fmaf(hk, w.w, acc.w);
    }
    float4 asv = *reinterpret_cast<const float4*>(&a2_src[j4 * 4]);
    float4 adv = *reinterpret_cast<const float4*>(&a2_dst[j4 * 4]);
    float ps = acc.x * asv.x + acc.y * asv.y + acc.z * asv.z + acc.w * asv.w;
    float pd = acc.x * adv.x + acc.y * adv.y + acc.z * adv.z + acc.w * adv.w;
    ps += __shfl_xor(ps, 1); ps += __shfl_xor(ps, 2);
    pd += __shfl_xor(pd, 1); pd += __shfl_xor(pd, 2);
    int gnode = n0 + node;
    if (gnode < N) {
        ushort4 p;
        p.x = f2bf(acc.x); p.y = f2bf(acc.y);
        p.z = f2bf(acc.z); p.w = f2bf(acc.w);
        *reinterpret_cast<ushort4*>(&g2b[(size_t)gnode * 16 + j4 * 4]) = p;
        if (j4 == 0) { as2[gnode] = ps; ad2[gnode] = pd; }
    }
}

// ---------------- layer-2 gather + bias + log_softmax: bf16 rows, 8 edges/iter ----------------
// lanes: slot = lane>>3 (8 edge slots); jd = lane&7 -> dims 2*jd,2*jd+1
__global__ __launch_bounds__(256) void gat2_kernel(const u16* __restrict__ g2b,
                                                   const float* __restrict__ as2,
                                                   const float* __restrict__ ad2,
                                                   const int* __restrict__ row_ptr,
                                                   const int* __restrict__ csr_src,
                                                   const float* __restrict__ b2,
                                                   float* __restrict__ out, int N) {
    int dst = blockIdx.x * 4 + (threadIdx.x >> 6);
    if (dst >= N) return;
    int lane = threadIdx.x & 63;
    int slot = lane >> 3, jd = lane & 7;
    float ad = ad2[dst];
    int start = row_ptr[dst], end = row_ptr[dst + 1];
    float acc0 = 0.f, acc1 = 0.f, ssum = 0.f;
    for (int base = start; base < end; base += 16) {
        #pragma unroll
        for (int g = 0; g < 2; ++g) {
            int idx = base + g * 8 + slot;
            bool ok = idx < end;
            int sidx = ok ? idx : end - 1;
            int s = csr_src[sidx];
            unsigned w = *reinterpret_cast<const unsigned*>(&g2b[(size_t)s * 16 + jd * 2]);
            float a = as2[s];
            float e = a + ad;
            e = fmaxf(e, NEG_SLOPE * e);
            float x = ok ? __expf(e) : 0.f;
            acc0 = fmaf(x, __uint_as_float(w << 16), acc0);
            acc1 = fmaf(x, __uint_as_float(w & 0xffff0000u), acc1);
            ssum += x;
        }
    }
    acc0 += __shfl_xor(acc0, 8); acc0 += __shfl_xor(acc0, 16); acc0 += __shfl_xor(acc0, 32);
    acc1 += __shfl_xor(acc1, 8); acc1 += __shfl_xor(acc1, 16); acc1 += __shfl_xor(acc1, 32);
    ssum += __shfl_xor(ssum, 8); ssum += __shfl_xor(ssum, 16); ssum += __shfl_xor(ssum, 32);
    float inv = 1.f / (ssum + EPS_F);
    float2 bb = *reinterpret_cast<const float2*>(&b2[jd * 2]);
    float v0 = acc0 * inv + bb.x;
    float v1 = acc1 * inv + bb.y;
    float mm = fmaxf(v0, v1);
    mm = fmaxf(mm, __shfl_xor(mm, 1));
    mm = fmaxf(mm, __shfl_xor(mm, 2));
    mm = fmaxf(mm, __shfl_xor(mm, 4));
    float es = __expf(v0 - mm) + __expf(v1 - mm);
    es += __shfl_xor(es, 1); es += __shfl_xor(es, 2); es += __shfl_xor(es, 4);
    float lse = mm + __logf(es);
    if (lane < 8) {
        *reinterpret_cast<float2*>(&out[(size_t)dst * 16 + jd * 2]) = make_float2(v0, v1);
        *reinterpret_cast<float2*>(&out[(size_t)N * 16 + (size_t)dst * 16 + jd * 2]) =
            make_float2(v0 - lse, v1 - lse);
    }
}

extern "C" void kernel_launch(void* const* d_in, const int* in_sizes, int n_in,
                              void* d_out, int out_size, void* d_ws, size_t ws_size,
                              hipStream_t stream) {
    const float* x      = (const float*)d_in[0];
    const int*   eidx   = (const int*)d_in[1];
    const float* W1     = (const float*)d_in[2];
    const float* a1_src = (const float*)d_in[3];
    const float* a1_dst = (const float*)d_in[4];
    const float* b1     = (const float*)d_in[5];
    const float* W2     = (const float*)d_in[6];
    const float* a2_src = (const float*)d_in[7];
    const float* a2_dst = (const float*)d_in[8];
    const float* b2     = (const float*)d_in[9];

    const int N = in_sizes[0] / 256;
    const int E = in_sizes[1] / 2;
    const int K = (N + 511) >> 9;
    const int* esrc = eidx;
    const int* edst = eidx + E;

    char* ws = (char*)d_ws;
    size_t off = 0;
    auto alloc = [&](size_t bytes) -> void* {
        void* p = ws + off;
        off += (bytes + 255) & ~size_t(255);
        return p;
    };
    u16* h1b         = (u16*)alloc((size_t)N * 64 * 2);
    float* as1       = (float*)alloc((size_t)N * 8 * 4);
    float* ad1       = (float*)alloc((size_t)N * 8 * 4);
    float* h2        = (float*)alloc((size_t)N * 64 * 4);
    u16* g2b         = (u16*)alloc((size_t)N * 16 * 2);
    float* as2       = (float*)alloc((size_t)N * 4);
    float* ad2       = (float*)alloc((size_t)N * 4);
    int* row_ptr     = (int*)alloc((size_t)(N + 1) * 4);
    int* csr_src     = (int*)alloc((size_t)E * 4);
    int* cursor      = (int*)alloc((size_t)K * 4);
    unsigned* bins   = (unsigned*)alloc((size_t)K * BCAP * 4);

    hipMemsetAsync(cursor, 0, (size_t)K * 4, stream);

    gemm1_kernel<<<(N + 63) / 64, 256, 0, stream>>>(x, W1, a1_src, a1_dst, h1b, as1, ad1, N);
    bin_kernel<<<(E + CHUNK - 1) / CHUNK, 256, 0, stream>>>(esrc, edst, cursor, bins, E, K);
    csr_kernel<<<K, 256, 0, stream>>>(bins, cursor, row_ptr, csr_src, N, K, E);
    gat1_kernel<<<(N + 3) / 4, 256, 0, stream>>>(h1b, as1, ad1, row_ptr, csr_src, b1, h2, N);
    gemm2_kernel<<<(N + 63) / 64, 256, 0, stream>>>(h2, W2, a2_src, a2_dst, g2b, as2, ad2, N);
    gat2_kernel<<<(N + 3) / 4, 256, 0, stream>>>(g2b, as2, ad2, row_ptr, csr_src, b2, (float*)d_out, N);
}

// Round 6
// 190.975 us; speedup vs baseline: 2.5091x; 1.0453x over previous
//
#include <hip/hip_runtime.h>

#define NEG_SLOPE 0.2f
#define EPS_F 1e-16f

#define K_MAX 256          // max buckets (N <= 131072)
#define BCAP 10240         // per-bucket capacity
#define CHUNK 4096         // edges per bin chunk

typedef unsigned short u16;
typedef __attribute__((ext_vector_type(8))) short bf16x8;
typedef __attribute__((ext_vector_type(4))) float f32x4;
typedef __attribute__((ext_vector_type(8))) unsigned short ushort8_t;

// round-to-nearest-even f32 -> bf16 (finite inputs)
static __device__ __forceinline__ u16 f2bf(float f) {
    unsigned u = __float_as_uint(f);
    unsigned r = (u + 0x7fffu + ((u >> 16) & 1u)) >> 16;
    return (u16)r;
}

// LDS swizzles: XOR row-low-bits into the 16B-slot bits of the byte offset (G4)
#define SWZ_A(r, kbyte) ((r) * 128 + ((kbyte) ^ (((r) & 7) << 4)))   // A: [128 rows][64 k] bf16
#define SWZ_B(c, kbyte) ((c) * 512 + ((kbyte) ^ (((c) & 7) << 4)))   // B: [64 cols][256 k] bf16

// ---------------- prep: W1 [256][64] f32 -> w1t [64][256] bf16 ----------------
__global__ __launch_bounds__(256) void prep_w1t_kernel(const float* __restrict__ W1,
                                                       u16* __restrict__ w1t) {
    int t = blockIdx.x * 256 + threadIdx.x;   // 16384 elems
    if (t < 16384) {
        int k = t >> 6, c = t & 63;
        w1t[c * 256 + k] = f2bf(W1[t]);
    }
}

// ---------------- Layer 1 GEMM via MFMA: h1b = bf16(x @ W1), as1/ad1 epilogue ----------------
// block = 256 thr = 4 waves; tile 128 rows x 64 cols; wave w owns rows [w*32, w*32+32)
__global__ __launch_bounds__(256) void gemm1_kernel(const float* __restrict__ x,
                                                    const u16* __restrict__ w1t,
                                                    const float* __restrict__ a1_src,
                                                    const float* __restrict__ a1_dst,
                                                    u16* __restrict__ h1b,
                                                    float* __restrict__ as1,
                                                    float* __restrict__ ad1, int N) {
    __shared__ u16 ldsA[8192];    // 16 KB: 128 x 64 bf16, swizzled
    __shared__ u16 ldsB[16384];   // 32 KB: 64 x 256 bf16 (W1^T), swizzled
    const int t = threadIdx.x;
    const int w = t >> 6, l = t & 63;
    const int n0 = blockIdx.x * 128;

    // stage all of W1^T into LDS once
    {
        int c = t >> 2, q = t & 3;
        #pragma unroll
        for (int i = 0; i < 8; ++i) {
            int kb = q * 128 + i * 16;    // byte offset within the 512B row
            ushort8_t v = *reinterpret_cast<const ushort8_t*>(&w1t[c * 256 + (kb >> 1)]);
            *reinterpret_cast<ushort8_t*>((char*)ldsB + SWZ_B(c, kb)) = v;
        }
    }

    f32x4 acc[2][4];
    #pragma unroll
    for (int m = 0; m < 2; ++m)
        #pragma unroll
        for (int n = 0; n < 4; ++n) acc[m][n] = (f32x4){0.f, 0.f, 0.f, 0.f};

    const int r0 = w * 32;
    const int arow = t >> 4;           // A-stage row slot 0..15
    const int ak4 = (t & 15) * 4;      // A-stage k offset 0..60

    for (int kc = 0; kc < 256; kc += 64) {
        __syncthreads();   // protect ldsA from previous iteration's readers (and B stage on iter 0)
        #pragma unroll
        for (int i = 0; i < 8; ++i) {
            int r = arow + 16 * i;
            int grow = n0 + r;
            float4 v = make_float4(0.f, 0.f, 0.f, 0.f);
            if (grow < N) v = *reinterpret_cast<const float4*>(&x[(size_t)grow * 256 + kc + ak4]);
            ushort4 p;
            p.x = f2bf(v.x); p.y = f2bf(v.y); p.z = f2bf(v.z); p.w = f2bf(v.w);
            *reinterpret_cast<ushort4*>((char*)ldsA + SWZ_A(r, ak4 * 2)) = p;
        }
        __syncthreads();

        #pragma unroll
        for (int kk = 0; kk < 64; kk += 32) {
            int klane = (kk + (l >> 4) * 8) * 2;          // byte offset of this lane's 8 k's
            bf16x8 a0 = *reinterpret_cast<bf16x8*>((char*)ldsA + SWZ_A(r0 + (l & 15), klane));
            bf16x8 a1 = *reinterpret_cast<bf16x8*>((char*)ldsA + SWZ_A(r0 + 16 + (l & 15), klane));
            #pragma unroll
            for (int n = 0; n < 4; ++n) {
                int c = n * 16 + (l & 15);
                bf16x8 b = *reinterpret_cast<bf16x8*>((char*)ldsB + SWZ_B(c, (kc + kk + (l >> 4) * 8) * 2));
                acc[0][n] = __builtin_amdgcn_mfma_f32_16x16x32_bf16(a0, b, acc[0][n], 0, 0, 0);
                acc[1][n] = __builtin_amdgcn_mfma_f32_16x16x32_bf16(a1, b, acc[1][n], 0, 0, 0);
            }
        }
    }

    // epilogue: bf16 store + per-head attention dots
    float asv[4], adv[4];
    #pragma unroll
    for (int n = 0; n < 4; ++n) {
        int c = n * 16 + (l & 15);
        asv[n] = a1_src[c];
        adv[n] = a1_dst[c];
    }
    #pragma unroll
    for (int m = 0; m < 2; ++m) {
        #pragma unroll
        for (int reg = 0; reg < 4; ++reg) {
            int row = n0 + r0 + m * 16 + (l >> 4) * 4 + reg;
            bool ok = row < N;
            #pragma unroll
            for (int n = 0; n < 4; ++n) {
                float v = acc[m][n][reg];
                if (ok) h1b[(size_t)row * 64 + n * 16 + (l & 15)] = f2bf(v);
                float s = v * asv[n];
                float d = v * adv[n];
                s += __shfl_xor(s, 1); s += __shfl_xor(s, 2); s += __shfl_xor(s, 4);
                d += __shfl_xor(d, 1); d += __shfl_xor(d, 2); d += __shfl_xor(d, 4);
                if (ok && (l & 7) == 0) {
                    int head = n * 2 + ((l & 15) >> 3);
                    as1[row * 8 + head] = s;
                    ad1[row * 8 + head] = d;
                }
            }
        }
    }
}

// ---------------- phase 1: bin edges into dst-buckets (coalesced writes) ----------------
__global__ __launch_bounds__(256) void bin_kernel(const int* __restrict__ src,
                                                  const int* __restrict__ dst,
                                                  int* __restrict__ cursor,
                                                  unsigned* __restrict__ bins,
                                                  int E, int K) {
    __shared__ int hist[K_MAX];
    __shared__ int lbase[K_MAX];
    __shared__ int goff[K_MAX];
    __shared__ int rk[K_MAX];
    __shared__ int sc[256];
    __shared__ unsigned pk[CHUNK];
    __shared__ unsigned short bid[CHUNK];

    int t = threadIdx.x;
    int nchunks = (E + CHUNK - 1) / CHUNK;
    for (int c = blockIdx.x; c < nchunks; c += gridDim.x) {
        int e0 = c * CHUNK;
        int ne = E - e0; if (ne > CHUNK) ne = CHUNK;
        for (int j = t; j < K_MAX; j += 256) { hist[j] = 0; rk[j] = 0; }
        __syncthreads();

        unsigned pks[16];
        int bks[16];
        #pragma unroll
        for (int k = 0; k < 16; ++k) {
            int i = e0 + t + k * 256;
            if (i < e0 + ne) {
                int d = dst[i];
                int s = src[i];
                int b = d >> 9;
                pks[k] = ((unsigned)s << 9) | (unsigned)(d & 511);
                bks[k] = b;
                atomicAdd(&hist[b], 1);
            } else {
                bks[k] = -1;
            }
        }
        __syncthreads();
        int hv = (t < K) ? hist[t] : 0;
        int val = hv;
        sc[t] = val; __syncthreads();
        for (int off = 1; off < 256; off <<= 1) {
            int add = (t >= off) ? sc[t - off] : 0;
            __syncthreads();
            val += add; sc[t] = val;
            __syncthreads();
        }
        if (t < K) {
            lbase[t] = val - hv;
            goff[t] = hv ? atomicAdd(&cursor[t], hv) : 0;
        }
        __syncthreads();
        #pragma unroll
        for (int k = 0; k < 16; ++k) {
            if (bks[k] >= 0) {
                int r = atomicAdd(&rk[bks[k]], 1);
                int p = lbase[bks[k]] + r;
                pk[p] = pks[k];
                bid[p] = (unsigned short)bks[k];
            }
        }
        __syncthreads();
        for (int j = t; j < ne; j += 256) {
            int b = bid[j];
            bins[(size_t)b * BCAP + goff[b] + (j - lbase[b])] = pk[j];
        }
        __syncthreads();
    }
}

// ---------------- phase 2: per-bucket CSR build (integrated bucket scan) ----------------
__global__ __launch_bounds__(256) void csr_kernel(const unsigned* __restrict__ bins,
                                                  const int* __restrict__ cursor,
                                                  int* __restrict__ row_ptr,
                                                  int* __restrict__ csr_src,
                                                  int N, int K, int E) {
    __shared__ unsigned pk[BCAP];
    __shared__ int hist[512];
    __shared__ int ex[512];
    __shared__ int rk2[512];
    __shared__ int sc[256];
    __shared__ int bb[256];
    int b = blockIdx.x;
    int t = threadIdx.x;

    int cv = (t < K) ? cursor[t] : 0;
    int val = cv;
    sc[t] = val; __syncthreads();
    for (int off = 1; off < 256; off <<= 1) {
        int add = (t >= off) ? sc[t - off] : 0;
        __syncthreads();
        val += add; sc[t] = val;
        __syncthreads();
    }
    bb[t] = val;
    __syncthreads();
    int base_g = (b == 0) ? 0 : bb[b - 1];
    int cnt = cursor[b];
    if (b == K - 1 && t == 0) row_ptr[N] = E;
    __syncthreads();

    for (int j = t; j < cnt; j += 256) pk[j] = bins[(size_t)b * BCAP + j];
    for (int j = t; j < 512; j += 256) { hist[j] = 0; rk2[j] = 0; }
    __syncthreads();
    for (int j = t; j < cnt; j += 256) atomicAdd(&hist[pk[j] & 511u], 1);
    __syncthreads();
    int h0 = hist[2 * t], h1v = hist[2 * t + 1];
    int s = h0 + h1v;
    int v2 = s;
    sc[t] = v2; __syncthreads();
    for (int off = 1; off < 256; off <<= 1) {
        int add = (t >= off) ? sc[t - off] : 0;
        __syncthreads();
        v2 += add; sc[t] = v2;
        __syncthreads();
    }
    int excl = v2 - s;
    ex[2 * t] = excl;
    ex[2 * t + 1] = excl + h0;
    __syncthreads();
    int nd0 = b << 9;
    for (int ld = t; ld < 512; ld += 256) {
        int d = nd0 + ld;
        if (d < N) row_ptr[d] = base_g + ex[ld];
    }
    for (int j = t; j < cnt; j += 256) {
        unsigned w = pk[j];
        int ld = (int)(w & 511u);
        int r = atomicAdd(&rk2[ld], 1);
        csr_src[base_g + ex[ld] + r] = (int)(w >> 9);
    }
}

// ---------------- layer-1 gather: bf16 rows, 2 edges per wave-iteration ----------------
__global__ __launch_bounds__(256) void gat1_kernel(const u16* __restrict__ h1b,
                                                   const float* __restrict__ as1,
                                                   const float* __restrict__ ad1,
                                                   const int* __restrict__ row_ptr,
                                                   const int* __restrict__ csr_src,
                                                   const float* __restrict__ b1,
                                                   float* __restrict__ h2, int N) {
    int dst = blockIdx.x * 4 + (threadIdx.x >> 6);
    if (dst >= N) return;
    int lane = threadIdx.x & 63;
    int half = lane >> 5;
    int d2 = lane & 31;
    int h = d2 >> 2;
    float ad = ad1[dst * 8 + h];
    int start = row_ptr[dst], end = row_ptr[dst + 1];
    float acc0 = 0.f, acc1 = 0.f, ssum = 0.f;
    int i = start;
    while (i < end) {
        int nb = end - i; if (nb > 64) nb = 64;
        int sreg = (lane < nb) ? csr_src[i + lane] : 0;
        int npair = nb >> 1;
        int np4 = npair & ~3;
        int kp = 0;
        for (; kp < np4; kp += 4) {
            int sv[4]; unsigned w[4]; float av[4];
            #pragma unroll
            for (int q = 0; q < 4; ++q) {
                int slo = __builtin_amdgcn_readlane(sreg, 2 * (kp + q));
                int shi = __builtin_amdgcn_readlane(sreg, 2 * (kp + q) + 1);
                sv[q] = half ? shi : slo;
            }
            #pragma unroll
            for (int q = 0; q < 4; ++q) {
                w[q] = *reinterpret_cast<const unsigned*>(&h1b[(size_t)sv[q] * 64 + d2 * 2]);
                av[q] = as1[sv[q] * 8 + h];
            }
            #pragma unroll
            for (int q = 0; q < 4; ++q) {
                float e = av[q] + ad;
                e = fmaxf(e, NEG_SLOPE * e);
                float x = __expf(e);
                acc0 = fmaf(x, __uint_as_float(w[q] << 16), acc0);
                acc1 = fmaf(x, __uint_as_float(w[q] & 0xffff0000u), acc1);
                ssum += x;
            }
        }
        for (; kp < npair; ++kp) {
            int slo = __builtin_amdgcn_readlane(sreg, 2 * kp);
            int shi = __builtin_amdgcn_readlane(sreg, 2 * kp + 1);
            int sv = half ? shi : slo;
            unsigned w = *reinterpret_cast<const unsigned*>(&h1b[(size_t)sv * 64 + d2 * 2]);
            float a = as1[sv * 8 + h];
            float e = a + ad;
            e = fmaxf(e, NEG_SLOPE * e);
            float x = __expf(e);
            acc0 = fmaf(x, __uint_as_float(w << 16), acc0);
            acc1 = fmaf(x, __uint_as_float(w & 0xffff0000u), acc1);
            ssum += x;
        }
        if (nb & 1) {
            int sv = __builtin_amdgcn_readlane(sreg, nb - 1);
            unsigned w = *reinterpret_cast<const unsigned*>(&h1b[(size_t)sv * 64 + d2 * 2]);
            float a = as1[sv * 8 + h];
            float e = a + ad;
            e = fmaxf(e, NEG_SLOPE * e);
            float x = half ? 0.f : __expf(e);
            acc0 = fmaf(x, __uint_as_float(w << 16), acc0);
            acc1 = fmaf(x, __uint_as_float(w & 0xffff0000u), acc1);
            ssum += x;
        }
        i += nb;
    }
    acc0 += __shfl_xor(acc0, 32);
    acc1 += __shfl_xor(acc1, 32);
    ssum += __shfl_xor(ssum, 32);
    if (half == 0) {
        float2 bb = *reinterpret_cast<const float2*>(&b1[d2 * 2]);
        float inv = 1.f / (ssum + EPS_F);
        float o0 = acc0 * inv + bb.x;
        float o1 = acc1 * inv + bb.y;
        o0 = (o0 > 0.f) ? o0 : (__expf(o0) - 1.f);   // ELU
        o1 = (o1 > 0.f) ? o1 : (__expf(o1) - 1.f);
        *reinterpret_cast<float2*>(&h2[(size_t)dst * 64 + d2 * 2]) = make_float2(o0, o1);
    }
}

// ---------------- Layer 2 GEMM: g2b = bf16(h2 @ W2), + src/dst dots ----------------
__global__ __launch_bounds__(256) void gemm2_kernel(const float* __restrict__ h2,
                                                    const float* __restrict__ W2,
                                                    const float* __restrict__ a2_src,
                                                    const float* __restrict__ a2_dst,
                                                    u16* __restrict__ g2b,
                                                    float* __restrict__ as2,
                                                    float* __restrict__ ad2, int N) {
    __shared__ float hs[64][68];
    __shared__ float ws[1024];
    int t = threadIdx.x;
    int n0 = blockIdx.x * 64;
    *reinterpret_cast<float4*>(&ws[t * 4]) = *reinterpret_cast<const float4*>(&W2[t * 4]);
    #pragma unroll
    for (int ii = 0; ii < 4; ++ii) {
        int fidx = (ii * 256 + t) * 4;
        int row = fidx >> 6;
        int col = fidx & 63;
        float4 v = make_float4(0.f, 0.f, 0.f, 0.f);
        if (n0 + row < N) v = *reinterpret_cast<const float4*>(&h2[(size_t)(n0 + row) * 64 + col]);
        *reinterpret_cast<float4*>(&hs[row][col]) = v;
    }
    __syncthreads();
    int node = t >> 2, j4 = t & 3;
    float4 acc = make_float4(0.f, 0.f, 0.f, 0.f);
    #pragma unroll
    for (int k = 0; k < 64; ++k) {
        float hk = hs[node][k];
        float4 w = *reinterpret_cast<const float4*>(&ws[k * 16 + j4 * 4]);
        acc.x = fmaf(hk, w.x, acc.x);
        acc.y = fmaf(hk, w.y, acc.y);
        acc.z = fmaf(hk, w.z, acc.z);
        acc.w = fmaf(hk, w.w, acc.w);
    }
    float4 asv = *reinterpret_cast<const float4*>(&a2_src[j4 * 4]);
    float4 adv = *reinterpret_cast<const float4*>(&a2_dst[j4 * 4]);
    float ps = acc.x * asv.x + acc.y * asv.y + acc.z * asv.z + acc.w * asv.w;
    float pd = acc.x * adv.x + acc.y * adv.y + acc.z * adv.z + acc.w * adv.w;
    ps += __shfl_xor(ps, 1); ps += __shfl_xor(ps, 2);
    pd += __shfl_xor(pd, 1); pd += __shfl_xor(pd, 2);
    int gnode = n0 + node;
    if (gnode < N) {
        ushort4 p;
        p.x = f2bf(acc.x); p.y = f2bf(acc.y);
        p.z = f2bf(acc.z); p.w = f2bf(acc.w);
        *reinterpret_cast<ushort4*>(&g2b[(size_t)gnode * 16 + j4 * 4]) = p;
        if (j4 == 0) { as2[gnode] = ps; ad2[gnode] = pd; }
    }
}

// ---------------- layer-2 gather + bias + log_softmax: bf16 rows, 8 edges/iter ----------------
__global__ __launch_bounds__(256) void gat2_kernel(const u16* __restrict__ g2b,
                                                   const float* __restrict__ as2,
                                                   const float* __restrict__ ad2,
                                                   const int* __restrict__ row_ptr,
                                                   const int* __restrict__ csr_src,
                                                   const float* __restrict__ b2,
                                                   float* __restrict__ out, int N) {
    int dst = blockIdx.x * 4 + (threadIdx.x >> 6);
    if (dst >= N) return;
    int lane = threadIdx.x & 63;
    int slot = lane >> 3, jd = lane & 7;
    float ad = ad2[dst];
    int start = row_ptr[dst], end = row_ptr[dst + 1];
    float acc0 = 0.f, acc1 = 0.f, ssum = 0.f;
    for (int base = start; base < end; base += 16) {
        #pragma unroll
        for (int g = 0; g < 2; ++g) {
            int idx = base + g * 8 + slot;
            bool ok = idx < end;
            int sidx = ok ? idx : end - 1;
            int s = csr_src[sidx];
            unsigned w = *reinterpret_cast<const unsigned*>(&g2b[(size_t)s * 16 + jd * 2]);
            float a = as2[s];
            float e = a + ad;
            e = fmaxf(e, NEG_SLOPE * e);
            float x = ok ? __expf(e) : 0.f;
            acc0 = fmaf(x, __uint_as_float(w << 16), acc0);
            acc1 = fmaf(x, __uint_as_float(w & 0xffff0000u), acc1);
            ssum += x;
        }
    }
    acc0 += __shfl_xor(acc0, 8); acc0 += __shfl_xor(acc0, 16); acc0 += __shfl_xor(acc0, 32);
    acc1 += __shfl_xor(acc1, 8); acc1 += __shfl_xor(acc1, 16); acc1 += __shfl_xor(acc1, 32);
    ssum += __shfl_xor(ssum, 8); ssum += __shfl_xor(ssum, 16); ssum += __shfl_xor(ssum, 32);
    float inv = 1.f / (ssum + EPS_F);
    float2 bb = *reinterpret_cast<const float2*>(&b2[jd * 2]);
    float v0 = acc0 * inv + bb.x;
    float v1 = acc1 * inv + bb.y;
    float mm = fmaxf(v0, v1);
    mm = fmaxf(mm, __shfl_xor(mm, 1));
    mm = fmaxf(mm, __shfl_xor(mm, 2));
    mm = fmaxf(mm, __shfl_xor(mm, 4));
    float es = __expf(v0 - mm) + __expf(v1 - mm);
    es += __shfl_xor(es, 1); es += __shfl_xor(es, 2); es += __shfl_xor(es, 4);
    float lse = mm + __logf(es);
    if (lane < 8) {
        *reinterpret_cast<float2*>(&out[(size_t)dst * 16 + jd * 2]) = make_float2(v0, v1);
        *reinterpret_cast<float2*>(&out[(size_t)N * 16 + (size_t)dst * 16 + jd * 2]) =
            make_float2(v0 - lse, v1 - lse);
    }
}

extern "C" void kernel_launch(void* const* d_in, const int* in_sizes, int n_in,
                              void* d_out, int out_size, void* d_ws, size_t ws_size,
                              hipStream_t stream) {
    const float* x      = (const float*)d_in[0];
    const int*   eidx   = (const int*)d_in[1];
    const float* W1     = (const float*)d_in[2];
    const float* a1_src = (const float*)d_in[3];
    const float* a1_dst = (const float*)d_in[4];
    const float* b1     = (const float*)d_in[5];
    const float* W2     = (const float*)d_in[6];
    const float* a2_src = (const float*)d_in[7];
    const float* a2_dst = (const float*)d_in[8];
    const float* b2     = (const float*)d_in[9];

    const int N = in_sizes[0] / 256;
    const int E = in_sizes[1] / 2;
    const int K = (N + 511) >> 9;
    const int* esrc = eidx;
    const int* edst = eidx + E;

    char* ws = (char*)d_ws;
    size_t off = 0;
    auto alloc = [&](size_t bytes) -> void* {
        void* p = ws + off;
        off += (bytes + 255) & ~size_t(255);
        return p;
    };
    u16* h1b         = (u16*)alloc((size_t)N * 64 * 2);
    u16* w1t         = (u16*)alloc((size_t)64 * 256 * 2);
    float* as1       = (float*)alloc((size_t)N * 8 * 4);
    float* ad1       = (float*)alloc((size_t)N * 8 * 4);
    float* h2        = (float*)alloc((size_t)N * 64 * 4);
    u16* g2b         = (u16*)alloc((size_t)N * 16 * 2);
    float* as2       = (float*)alloc((size_t)N * 4);
    float* ad2       = (float*)alloc((size_t)N * 4);
    int* row_ptr     = (int*)alloc((size_t)(N + 1) * 4);
    int* csr_src     = (int*)alloc((size_t)E * 4);
    int* cursor      = (int*)alloc((size_t)K * 4);
    unsigned* bins   = (unsigned*)alloc((size_t)K * BCAP * 4);

    hipMemsetAsync(cursor, 0, (size_t)K * 4, stream);

    prep_w1t_kernel<<<64, 256, 0, stream>>>(W1, w1t);
    gemm1_kernel<<<(N + 127) / 128, 256, 0, stream>>>(x, w1t, a1_src, a1_dst, h1b, as1, ad1, N);
    bin_kernel<<<(E + CHUNK - 1) / CHUNK, 256, 0, stream>>>(esrc, edst, cursor, bins, E, K);
    csr_kernel<<<K, 256, 0, stream>>>(bins, cursor, row_ptr, csr_src, N, K, E);
    gat1_kernel<<<(N + 3) / 4, 256, 0, stream>>>(h1b, as1, ad1, row_ptr, csr_src, b1, h2, N);
    gemm2_kernel<<<(N + 63) / 64, 256, 0, stream>>>(h2, W2, a2_src, a2_dst, g2b, as2, ad2, N);
    gat2_kernel<<<(N + 3) / 4, 256, 0, stream>>>(g2b, as2, ad2, row_ptr, csr_src, b2, (float*)d_out, N);
}

// Round 7
// 178.919 us; speedup vs baseline: 2.6782x; 1.0674x over previous
//
#include <hip/hip_runtime.h>

#define NEG_SLOPE 0.2f
#define EPS_F 1e-16f

#define K_MAX 256          // max buckets (N <= 131072)
#define BCAP 10240         // per-bucket capacity
#define CHUNK 4096         // edges per bin chunk

typedef unsigned short u16;
typedef __attribute__((ext_vector_type(8))) short bf16x8;
typedef __attribute__((ext_vector_type(4))) float f32x4;
typedef __attribute__((ext_vector_type(8))) unsigned short ushort8_t;

// round-to-nearest-even f32 -> bf16 (finite inputs)
static __device__ __forceinline__ u16 f2bf(float f) {
    unsigned u = __float_as_uint(f);
    unsigned r = (u + 0x7fffu + ((u >> 16) & 1u)) >> 16;
    return (u16)r;
}

// LDS swizzles: XOR row-low-bits into the 16B-slot bits of the byte offset (G4)
#define SWZ_A(r, kbyte) ((r) * 128 + ((kbyte) ^ (((r) & 7) << 4)))   // A: [128 rows][64 k] bf16
#define SWZ_B(c, kbyte) ((c) * 512 + ((kbyte) ^ (((c) & 7) << 4)))   // B: [64 cols][256 k] bf16

// ---------------- prep: W1 [256][64] f32 -> w1t [64][256] bf16 ----------------
__global__ __launch_bounds__(256) void prep_w1t_kernel(const float* __restrict__ W1,
                                                       u16* __restrict__ w1t) {
    int t = blockIdx.x * 256 + threadIdx.x;   // 16384 elems
    if (t < 16384) {
        int k = t >> 6, c = t & 63;
        w1t[c * 256 + k] = f2bf(W1[t]);
    }
}

// ---------------- Layer 1 GEMM via MFMA, async-staged (T14) ----------------
// block = 256 thr = 4 waves; tile 128 rows x 64 cols; wave w owns rows [w*32, w*32+32)
__global__ __launch_bounds__(256) void gemm1_kernel(const float* __restrict__ x,
                                                    const u16* __restrict__ w1t,
                                                    const float* __restrict__ a1_src,
                                                    const float* __restrict__ a1_dst,
                                                    u16* __restrict__ h1b,
                                                    float* __restrict__ as1,
                                                    float* __restrict__ ad1, int N) {
    __shared__ u16 ldsA[8192];    // 16 KB: 128 x 64 bf16, swizzled
    __shared__ u16 ldsB[16384];   // 32 KB: 64 x 256 bf16 (W1^T), swizzled
    const int t = threadIdx.x;
    const int w = t >> 6, l = t & 63;
    const int n0 = blockIdx.x * 128;

    const int arow = t >> 4;           // A-stage row slot 0..15
    const int ak4 = (t & 15) * 4;      // A-stage k offset 0..60

    // issue chunk-0 x loads FIRST (in flight during B staging)
    float4 v[8];
    #pragma unroll
    for (int i = 0; i < 8; ++i) {
        int grow = n0 + arow + 16 * i;
        v[i] = make_float4(0.f, 0.f, 0.f, 0.f);
        if (grow < N) v[i] = *reinterpret_cast<const float4*>(&x[(size_t)grow * 256 + ak4]);
    }

    // stage all of W1^T into LDS once
    {
        int c = t >> 2, q = t & 3;
        #pragma unroll
        for (int i = 0; i < 8; ++i) {
            int kb = q * 128 + i * 16;    // byte offset within the 512B row
            ushort8_t vb = *reinterpret_cast<const ushort8_t*>(&w1t[c * 256 + (kb >> 1)]);
            *reinterpret_cast<ushort8_t*>((char*)ldsB + SWZ_B(c, kb)) = vb;
        }
    }

    f32x4 acc[2][4];
    #pragma unroll
    for (int m = 0; m < 2; ++m)
        #pragma unroll
        for (int n = 0; n < 4; ++n) acc[m][n] = (f32x4){0.f, 0.f, 0.f, 0.f};

    const int r0 = w * 32;

    for (int kc = 0; kc < 256; kc += 64) {
        // convert + store current chunk (vmcnt wait lands here, after a full
        // MFMA phase of overlap for chunks >0)
        #pragma unroll
        for (int i = 0; i < 8; ++i) {
            int r = arow + 16 * i;
            ushort4 p;
            p.x = f2bf(v[i].x); p.y = f2bf(v[i].y); p.z = f2bf(v[i].z); p.w = f2bf(v[i].w);
            *reinterpret_cast<ushort4*>((char*)ldsA + SWZ_A(r, ak4 * 2)) = p;
        }
        __syncthreads();

        // prefetch next chunk into regs (issue-early; no LDS touch)
        if (kc < 192) {
            #pragma unroll
            for (int i = 0; i < 8; ++i) {
                int grow = n0 + arow + 16 * i;
                float4 nv = make_float4(0.f, 0.f, 0.f, 0.f);
                if (grow < N)
                    nv = *reinterpret_cast<const float4*>(&x[(size_t)grow * 256 + kc + 64 + ak4]);
                v[i] = nv;
            }
        }

        // MFMA phase on current chunk
        #pragma unroll
        for (int kk = 0; kk < 64; kk += 32) {
            int klane = (kk + (l >> 4) * 8) * 2;          // byte offset of this lane's 8 k's
            bf16x8 a0 = *reinterpret_cast<bf16x8*>((char*)ldsA + SWZ_A(r0 + (l & 15), klane));
            bf16x8 a1 = *reinterpret_cast<bf16x8*>((char*)ldsA + SWZ_A(r0 + 16 + (l & 15), klane));
            #pragma unroll
            for (int n = 0; n < 4; ++n) {
                int c = n * 16 + (l & 15);
                bf16x8 b = *reinterpret_cast<bf16x8*>((char*)ldsB + SWZ_B(c, (kc + kk + (l >> 4) * 8) * 2));
                acc[0][n] = __builtin_amdgcn_mfma_f32_16x16x32_bf16(a0, b, acc[0][n], 0, 0, 0);
                acc[1][n] = __builtin_amdgcn_mfma_f32_16x16x32_bf16(a1, b, acc[1][n], 0, 0, 0);
            }
        }
        __syncthreads();
    }

    // epilogue: bf16 store + per-head attention dots
    float asv[4], adv[4];
    #pragma unroll
    for (int n = 0; n < 4; ++n) {
        int c = n * 16 + (l & 15);
        asv[n] = a1_src[c];
        adv[n] = a1_dst[c];
    }
    #pragma unroll
    for (int m = 0; m < 2; ++m) {
        #pragma unroll
        for (int reg = 0; reg < 4; ++reg) {
            int row = n0 + r0 + m * 16 + (l >> 4) * 4 + reg;
            bool ok = row < N;
            #pragma unroll
            for (int n = 0; n < 4; ++n) {
                float vv = acc[m][n][reg];
                if (ok) h1b[(size_t)row * 64 + n * 16 + (l & 15)] = f2bf(vv);
                float s = vv * asv[n];
                float d = vv * adv[n];
                s += __shfl_xor(s, 1); s += __shfl_xor(s, 2); s += __shfl_xor(s, 4);
                d += __shfl_xor(d, 1); d += __shfl_xor(d, 2); d += __shfl_xor(d, 4);
                if (ok && (l & 7) == 0) {
                    int head = n * 2 + ((l & 15) >> 3);
                    as1[row * 8 + head] = s;
                    ad1[row * 8 + head] = d;
                }
            }
        }
    }
}

// ---------------- phase 1: bin edges into dst-buckets (coalesced writes) ----------------
__global__ __launch_bounds__(256) void bin_kernel(const int* __restrict__ src,
                                                  const int* __restrict__ dst,
                                                  int* __restrict__ cursor,
                                                  unsigned* __restrict__ bins,
                                                  int E, int K) {
    __shared__ int hist[K_MAX];
    __shared__ int lbase[K_MAX];
    __shared__ int goff[K_MAX];
    __shared__ int rk[K_MAX];
    __shared__ int sc[256];
    __shared__ unsigned pk[CHUNK];
    __shared__ unsigned short bid[CHUNK];

    int t = threadIdx.x;
    int nchunks = (E + CHUNK - 1) / CHUNK;
    for (int c = blockIdx.x; c < nchunks; c += gridDim.x) {
        int e0 = c * CHUNK;
        int ne = E - e0; if (ne > CHUNK) ne = CHUNK;
        for (int j = t; j < K_MAX; j += 256) { hist[j] = 0; rk[j] = 0; }
        __syncthreads();

        unsigned pks[16];
        int bks[16];
        #pragma unroll
        for (int k = 0; k < 16; ++k) {
            int i = e0 + t + k * 256;
            if (i < e0 + ne) {
                int d = dst[i];
                int s = src[i];
                int b = d >> 9;
                pks[k] = ((unsigned)s << 9) | (unsigned)(d & 511);
                bks[k] = b;
                atomicAdd(&hist[b], 1);
            } else {
                bks[k] = -1;
            }
        }
        __syncthreads();
        int hv = (t < K) ? hist[t] : 0;
        int val = hv;
        sc[t] = val; __syncthreads();
        for (int off = 1; off < 256; off <<= 1) {
            int add = (t >= off) ? sc[t - off] : 0;
            __syncthreads();
            val += add; sc[t] = val;
            __syncthreads();
        }
        if (t < K) {
            lbase[t] = val - hv;
            goff[t] = hv ? atomicAdd(&cursor[t], hv) : 0;
        }
        __syncthreads();
        #pragma unroll
        for (int k = 0; k < 16; ++k) {
            if (bks[k] >= 0) {
                int r = atomicAdd(&rk[bks[k]], 1);
                int p = lbase[bks[k]] + r;
                pk[p] = pks[k];
                bid[p] = (unsigned short)bks[k];
            }
        }
        __syncthreads();
        for (int j = t; j < ne; j += 256) {
            int b = bid[j];
            bins[(size_t)b * BCAP + goff[b] + (j - lbase[b])] = pk[j];
        }
        __syncthreads();
    }
}

// ---------------- phase 2: per-bucket CSR build (integrated bucket scan) ----------------
__global__ __launch_bounds__(256) void csr_kernel(const unsigned* __restrict__ bins,
                                                  const int* __restrict__ cursor,
                                                  int* __restrict__ row_ptr,
                                                  int* __restrict__ csr_src,
                                                  int N, int K, int E) {
    __shared__ unsigned pk[BCAP];
    __shared__ int hist[512];
    __shared__ int ex[512];
    __shared__ int rk2[512];
    __shared__ int sc[256];
    __shared__ int bb[256];
    int b = blockIdx.x;
    int t = threadIdx.x;

    int cv = (t < K) ? cursor[t] : 0;
    int val = cv;
    sc[t] = val; __syncthreads();
    for (int off = 1; off < 256; off <<= 1) {
        int add = (t >= off) ? sc[t - off] : 0;
        __syncthreads();
        val += add; sc[t] = val;
        __syncthreads();
    }
    bb[t] = val;
    __syncthreads();
    int base_g = (b == 0) ? 0 : bb[b - 1];
    int cnt = cursor[b];
    if (b == K - 1 && t == 0) row_ptr[N] = E;
    __syncthreads();

    for (int j = t; j < cnt; j += 256) pk[j] = bins[(size_t)b * BCAP + j];
    for (int j = t; j < 512; j += 256) { hist[j] = 0; rk2[j] = 0; }
    __syncthreads();
    for (int j = t; j < cnt; j += 256) atomicAdd(&hist[pk[j] & 511u], 1);
    __syncthreads();
    int h0 = hist[2 * t], h1v = hist[2 * t + 1];
    int s = h0 + h1v;
    int v2 = s;
    sc[t] = v2; __syncthreads();
    for (int off = 1; off < 256; off <<= 1) {
        int add = (t >= off) ? sc[t - off] : 0;
        __syncthreads();
        v2 += add; sc[t] = v2;
        __syncthreads();
    }
    int excl = v2 - s;
    ex[2 * t] = excl;
    ex[2 * t + 1] = excl + h0;
    __syncthreads();
    int nd0 = b << 9;
    for (int ld = t; ld < 512; ld += 256) {
        int d = nd0 + ld;
        if (d < N) row_ptr[d] = base_g + ex[ld];
    }
    for (int j = t; j < cnt; j += 256) {
        unsigned w = pk[j];
        int ld = (int)(w & 511u);
        int r = atomicAdd(&rk2[ld], 1);
        csr_src[base_g + ex[ld] + r] = (int)(w >> 9);
    }
}

// ---------------- layer-1 gather: bf16 rows, 2 edges per wave-iteration ----------------
__global__ __launch_bounds__(256) void gat1_kernel(const u16* __restrict__ h1b,
                                                   const float* __restrict__ as1,
                                                   const float* __restrict__ ad1,
                                                   const int* __restrict__ row_ptr,
                                                   const int* __restrict__ csr_src,
                                                   const float* __restrict__ b1,
                                                   float* __restrict__ h2, int N) {
    int dst = blockIdx.x * 4 + (threadIdx.x >> 6);
    if (dst >= N) return;
    int lane = threadIdx.x & 63;
    int half = lane >> 5;
    int d2 = lane & 31;
    int h = d2 >> 2;
    float ad = ad1[dst * 8 + h];
    int start = row_ptr[dst], end = row_ptr[dst + 1];
    float acc0 = 0.f, acc1 = 0.f, ssum = 0.f;
    int i = start;
    while (i < end) {
        int nb = end - i; if (nb > 64) nb = 64;
        int sreg = (lane < nb) ? csr_src[i + lane] : 0;
        int npair = nb >> 1;
        int np4 = npair & ~3;
        int kp = 0;
        for (; kp < np4; kp += 4) {
            int sv[4]; unsigned w[4]; float av[4];
            #pragma unroll
            for (int q = 0; q < 4; ++q) {
                int slo = __builtin_amdgcn_readlane(sreg, 2 * (kp + q));
                int shi = __builtin_amdgcn_readlane(sreg, 2 * (kp + q) + 1);
                sv[q] = half ? shi : slo;
            }
            #pragma unroll
            for (int q = 0; q < 4; ++q) {
                w[q] = *reinterpret_cast<const unsigned*>(&h1b[(size_t)sv[q] * 64 + d2 * 2]);
                av[q] = as1[sv[q] * 8 + h];
            }
            #pragma unroll
            for (int q = 0; q < 4; ++q) {
                float e = av[q] + ad;
                e = fmaxf(e, NEG_SLOPE * e);
                float x = __expf(e);
                acc0 = fmaf(x, __uint_as_float(w[q] << 16), acc0);
                acc1 = fmaf(x, __uint_as_float(w[q] & 0xffff0000u), acc1);
                ssum += x;
            }
        }
        for (; kp < npair; ++kp) {
            int slo = __builtin_amdgcn_readlane(sreg, 2 * kp);
            int shi = __builtin_amdgcn_readlane(sreg, 2 * kp + 1);
            int sv = half ? shi : slo;
            unsigned w = *reinterpret_cast<const unsigned*>(&h1b[(size_t)sv * 64 + d2 * 2]);
            float a = as1[sv * 8 + h];
            float e = a + ad;
            e = fmaxf(e, NEG_SLOPE * e);
            float x = __expf(e);
            acc0 = fmaf(x, __uint_as_float(w << 16), acc0);
            acc1 = fmaf(x, __uint_as_float(w & 0xffff0000u), acc1);
            ssum += x;
        }
        if (nb & 1) {
            int sv = __builtin_amdgcn_readlane(sreg, nb - 1);
            unsigned w = *reinterpret_cast<const unsigned*>(&h1b[(size_t)sv * 64 + d2 * 2]);
            float a = as1[sv * 8 + h];
            float e = a + ad;
            e = fmaxf(e, NEG_SLOPE * e);
            float x = half ? 0.f : __expf(e);
            acc0 = fmaf(x, __uint_as_float(w << 16), acc0);
            acc1 = fmaf(x, __uint_as_float(w & 0xffff0000u), acc1);
            ssum += x;
        }
        i += nb;
    }
    acc0 += __shfl_xor(acc0, 32);
    acc1 += __shfl_xor(acc1, 32);
    ssum += __shfl_xor(ssum, 32);
    if (half == 0) {
        float2 bb = *reinterpret_cast<const float2*>(&b1[d2 * 2]);
        float inv = 1.f / (ssum + EPS_F);
        float o0 = acc0 * inv + bb.x;
        float o1 = acc1 * inv + bb.y;
        o0 = (o0 > 0.f) ? o0 : (__expf(o0) - 1.f);   // ELU
        o1 = (o1 > 0.f) ? o1 : (__expf(o1) - 1.f);
        *reinterpret_cast<float2*>(&h2[(size_t)dst * 64 + d2 * 2]) = make_float2(o0, o1);
    }
}

// ---------------- Layer 2 GEMM: g2b = bf16(h2 @ W2), + src/dst dots ----------------
__global__ __launch_bounds__(256) void gemm2_kernel(const float* __restrict__ h2,
                                                    const float* __restrict__ W2,
                                                    const float* __restrict__ a2_src,
                                                    const float* __restrict__ a2_dst,
                                                    u16* __restrict__ g2b,
                                                    float* __restrict__ as2,
                                                    float* __restrict__ ad2, int N) {
    __shared__ float hs[64][68];
    __shared__ float ws[1024];
    int t = threadIdx.x;
    int n0 = blockIdx.x * 64;
    *reinterpret_cast<float4*>(&ws[t * 4]) = *reinterpret_cast<const float4*>(&W2[t * 4]);
    #pragma unroll
    for (int ii = 0; ii < 4; ++ii) {
        int fidx = (ii * 256 + t) * 4;
        int row = fidx >> 6;
        int col = fidx & 63;
        float4 v = make_float4(0.f, 0.f, 0.f, 0.f);
        if (n0 + row < N) v = *reinterpret_cast<const float4*>(&h2[(size_t)(n0 + row) * 64 + col]);
        *reinterpret_cast<float4*>(&hs[row][col]) = v;
    }
    __syncthreads();
    int node = t >> 2, j4 = t & 3;
    float4 acc = make_float4(0.f, 0.f, 0.f, 0.f);
    #pragma unroll
    for (int k = 0; k < 64; ++k) {
        float hk = hs[node][k];
        float4 w = *reinterpret_cast<const float4*>(&ws[k * 16 + j4 * 4]);
        acc.x = fmaf(hk, w.x, acc.x);
        acc.y = fmaf(hk, w.y, acc.y);
        acc.z = fmaf(hk, w.z, acc.z);
        acc.w = fmaf(hk, w.w, acc.w);
    }
    float4 asv = *reinterpret_cast<const float4*>(&a2_src[j4 * 4]);
    float4 adv = *reinterpret_cast<const float4*>(&a2_dst[j4 * 4]);
    float ps = acc.x * asv.x + acc.y * asv.y + acc.z * asv.z + acc.w * asv.w;
    float pd = acc.x * adv.x + acc.y * adv.y + acc.z * adv.z + acc.w * adv.w;
    ps += __shfl_xor(ps, 1); ps += __shfl_xor(ps, 2);
    pd += __shfl_xor(pd, 1); pd += __shfl_xor(pd, 2);
    int gnode = n0 + node;
    if (gnode < N) {
        ushort4 p;
        p.x = f2bf(acc.x); p.y = f2bf(acc.y);
        p.z = f2bf(acc.z); p.w = f2bf(acc.w);
        *reinterpret_cast<ushort4*>(&g2b[(size_t)gnode * 16 + j4 * 4]) = p;
        if (j4 == 0) { as2[gnode] = ps; ad2[gnode] = pd; }
    }
}

// ---------------- layer-2 gather + bias + log_softmax: bf16 rows, 8 edges/iter ----------------
__global__ __launch_bounds__(256) void gat2_kernel(const u16* __restrict__ g2b,
                                                   const float* __restrict__ as2,
                                                   const float* __restrict__ ad2,
                                                   const int* __restrict__ row_ptr,
                                                   const int* __restrict__ csr_src,
                                                   const float* __restrict__ b2,
                                                   float* __restrict__ out, int N) {
    int dst = blockIdx.x * 4 + (threadIdx.x >> 6);
    if (dst >= N) return;
    int lane = threadIdx.x & 63;
    int slot = lane >> 3, jd = lane & 7;
    float ad = ad2[dst];
    int start = row_ptr[dst], end = row_ptr[dst + 1];
    float acc0 = 0.f, acc1 = 0.f, ssum = 0.f;
    for (int base = start; base < end; base += 16) {
        #pragma unroll
        for (int g = 0; g < 2; ++g) {
            int idx = base + g * 8 + slot;
            bool ok = idx < end;
            int sidx = ok ? idx : end - 1;
            int s = csr_src[sidx];
            unsigned w = *reinterpret_cast<const unsigned*>(&g2b[(size_t)s * 16 + jd * 2]);
            float a = as2[s];
            float e = a + ad;
            e = fmaxf(e, NEG_SLOPE * e);
            float x = ok ? __expf(e) : 0.f;
            acc0 = fmaf(x, __uint_as_float(w << 16), acc0);
            acc1 = fmaf(x, __uint_as_float(w & 0xffff0000u), acc1);
            ssum += x;
        }
    }
    acc0 += __shfl_xor(acc0, 8); acc0 += __shfl_xor(acc0, 16); acc0 += __shfl_xor(acc0, 32);
    acc1 += __shfl_xor(acc1, 8); acc1 += __shfl_xor(acc1, 16); acc1 += __shfl_xor(acc1, 32);
    ssum += __shfl_xor(ssum, 8); ssum += __shfl_xor(ssum, 16); ssum += __shfl_xor(ssum, 32);
    float inv = 1.f / (ssum + EPS_F);
    float2 bb = *reinterpret_cast<const float2*>(&b2[jd * 2]);
    float v0 = acc0 * inv + bb.x;
    float v1 = acc1 * inv + bb.y;
    float mm = fmaxf(v0, v1);
    mm = fmaxf(mm, __shfl_xor(mm, 1));
    mm = fmaxf(mm, __shfl_xor(mm, 2));
    mm = fmaxf(mm, __shfl_xor(mm, 4));
    float es = __expf(v0 - mm) + __expf(v1 - mm);
    es += __shfl_xor(es, 1); es += __shfl_xor(es, 2); es += __shfl_xor(es, 4);
    float lse = mm + __logf(es);
    if (lane < 8) {
        *reinterpret_cast<float2*>(&out[(size_t)dst * 16 + jd * 2]) = make_float2(v0, v1);
        *reinterpret_cast<float2*>(&out[(size_t)N * 16 + (size_t)dst * 16 + jd * 2]) =
            make_float2(v0 - lse, v1 - lse);
    }
}

extern "C" void kernel_launch(void* const* d_in, const int* in_sizes, int n_in,
                              void* d_out, int out_size, void* d_ws, size_t ws_size,
                              hipStream_t stream) {
    const float* x      = (const float*)d_in[0];
    const int*   eidx   = (const int*)d_in[1];
    const float* W1     = (const float*)d_in[2];
    const float* a1_src = (const float*)d_in[3];
    const float* a1_dst = (const float*)d_in[4];
    const float* b1     = (const float*)d_in[5];
    const float* W2     = (const float*)d_in[6];
    const float* a2_src = (const float*)d_in[7];
    const float* a2_dst = (const float*)d_in[8];
    const float* b2     = (const float*)d_in[9];

    const int N = in_sizes[0] / 256;
    const int E = in_sizes[1] / 2;
    const int K = (N + 511) >> 9;
    const int* esrc = eidx;
    const int* edst = eidx + E;

    char* ws = (char*)d_ws;
    size_t off = 0;
    auto alloc = [&](size_t bytes) -> void* {
        void* p = ws + off;
        off += (bytes + 255) & ~size_t(255);
        return p;
    };
    u16* h1b         = (u16*)alloc((size_t)N * 64 * 2);
    u16* w1t         = (u16*)alloc((size_t)64 * 256 * 2);
    float* as1       = (float*)alloc((size_t)N * 8 * 4);
    float* ad1       = (float*)alloc((size_t)N * 8 * 4);
    float* h2        = (float*)alloc((size_t)N * 64 * 4);
    u16* g2b         = (u16*)alloc((size_t)N * 16 * 2);
    float* as2       = (float*)alloc((size_t)N * 4);
    float* ad2       = (float*)alloc((size_t)N * 4);
    int* row_ptr     = (int*)alloc((size_t)(N + 1) * 4);
    int* csr_src     = (int*)alloc((size_t)E * 4);
    int* cursor      = (int*)alloc((size_t)K * 4);
    unsigned* bins   = (unsigned*)alloc((size_t)K * BCAP * 4);

    hipMemsetAsync(cursor, 0, (size_t)K * 4, stream);

    prep_w1t_kernel<<<64, 256, 0, stream>>>(W1, w1t);
    gemm1_kernel<<<(N + 127) / 128, 256, 0, stream>>>(x, w1t, a1_src, a1_dst, h1b, as1, ad1, N);
    bin_kernel<<<(E + CHUNK - 1) / CHUNK, 256, 0, stream>>>(esrc, edst, cursor, bins, E, K);
    csr_kernel<<<K, 256, 0, stream>>>(bins, cursor, row_ptr, csr_src, N, K, E);
    gat1_kernel<<<(N + 3) / 4, 256, 0, stream>>>(h1b, as1, ad1, row_ptr, csr_src, b1, h2, N);
    gemm2_kernel<<<(N + 63) / 64, 256, 0, stream>>>(h2, W2, a2_src, a2_dst, g2b, as2, ad2, N);
    gat2_kernel<<<(N + 3) / 4, 256, 0, stream>>>(g2b, as2, ad2, row_ptr, csr_src, b2, (float*)d_out, N);
}